// Round 1
// baseline (226.627 us; speedup 1.0000x reference)
//
#include <hip/hip_runtime.h>
#include <cmath>

#define HW 4096
#define C_ 256
#define NN 49
#define KIN 305   // 49 + 256

__device__ __forceinline__ int refl(int i) { return i < 0 ? -i : (i > 63 ? 126 - i : i); }
__device__ __forceinline__ float sigmoidf_(float x) { return 1.f / (1.f + __expf(-x)); }

// ---------------------------------------------------------------- transpose
// src: [B][R][Cc] -> dst: [B][Cc][R]
__global__ __launch_bounds__(256) void transpose_k(const float* __restrict__ src,
                                                   float* __restrict__ dst,
                                                   int R, int Cc)
{
    __shared__ float tile[32][33];
    int b = blockIdx.z;
    const float* s = src + (size_t)b * R * Cc;
    float* d = dst + (size_t)b * R * Cc;
    int c0 = blockIdx.x * 32, r0 = blockIdx.y * 32;
    int tx = threadIdx.x & 31, ty = threadIdx.x >> 5;   // 32 x 8
    #pragma unroll
    for (int i = 0; i < 32; i += 8)
        tile[ty + i][tx] = s[(size_t)(r0 + ty + i) * Cc + c0 + tx];
    __syncthreads();
    #pragma unroll
    for (int i = 0; i < 32; i += 8)
        d[(size_t)(c0 + ty + i) * R + r0 + tx] = tile[tx][ty + i];
}

// ---------------------------------------------------------------- spatial kernel
__global__ void sk_kernel(const float* __restrict__ sigma, float* __restrict__ sk)
{
    int n = threadIdx.x;
    if (n < NN) {
        int i = n / 7, j = n % 7;
        float xg = (i - 3) * (1.f / 3.f), yg = (j - 3) * (1.f / 3.f);
        float s = sigma[0];
        sk[n] = __expf(-(xg * xg + yg * yg) / (2.f * s * s));
    }
}

// ---------------------------------------------------------------- fused conv1x1 (+LN (+SiLU))
// xT: [B*HW][256] channel-last.  w: [256][256] row-major [o][i].
// OUT_CF=false -> y as [B*HW][256]; OUT_CF=true -> y as [B][256][HW].
template<bool LN, bool SILU, bool OUT_CF>
__global__ __launch_bounds__(256) void conv256_k(const float* __restrict__ xT,
                                                 const float* __restrict__ w,
                                                 const float* __restrict__ bias,
                                                 const float* __restrict__ g,
                                                 const float* __restrict__ be,
                                                 float* __restrict__ y)
{
    constexpr int PIX = 16, KC = 32;
    __shared__ float wl[KC][C_ + 4];   // [k][o], padded
    __shared__ float xl[KC][20];       // [k][p], padded (16B-aligned rows)
    int t = threadIdx.x;
    int wid = t >> 6;
    int o0 = (t & 63) * 4;             // 4 consecutive output channels
    int pg = wid;                      // wave -> 4 pixels
    long q0 = (long)blockIdx.x * PIX;

    float4 acc[4];
    #pragma unroll
    for (int p = 0; p < 4; ++p) acc[p] = make_float4(0.f, 0.f, 0.f, 0.f);

    for (int kc = 0; kc < C_; kc += KC) {
        __syncthreads();
        {   // stage W chunk transposed: wl[k][o]
            int kk4 = (t & 7) * 4;
            int orow = t >> 3;
            #pragma unroll
            for (int it = 0; it < 8; ++it) {
                int oo = orow + it * 32;
                float4 wv = *(const float4*)(w + (size_t)oo * C_ + kc + kk4);
                wl[kk4 + 0][oo] = wv.x;
                wl[kk4 + 1][oo] = wv.y;
                wl[kk4 + 2][oo] = wv.z;
                wl[kk4 + 3][oo] = wv.w;
            }
        }
        {   // stage X chunk: xl[k][p]
            int p = t >> 4;
            int kk = (t & 15) * 2;
            float2 xv = *(const float2*)(xT + (q0 + p) * (size_t)C_ + kc + kk);
            xl[kk][p] = xv.x;
            xl[kk + 1][p] = xv.y;
        }
        __syncthreads();
        #pragma unroll
        for (int k = 0; k < KC; ++k) {
            float4 wv = *(const float4*)&wl[k][o0];
            float4 xv = *(const float4*)&xl[k][pg * 4];
            acc[0].x += wv.x * xv.x; acc[0].y += wv.y * xv.x; acc[0].z += wv.z * xv.x; acc[0].w += wv.w * xv.x;
            acc[1].x += wv.x * xv.y; acc[1].y += wv.y * xv.y; acc[1].z += wv.z * xv.y; acc[1].w += wv.w * xv.y;
            acc[2].x += wv.x * xv.z; acc[2].y += wv.y * xv.z; acc[2].z += wv.z * xv.z; acc[2].w += wv.w * xv.z;
            acc[3].x += wv.x * xv.w; acc[3].y += wv.y * xv.w; acc[3].z += wv.z * xv.w; acc[3].w += wv.w * xv.w;
        }
    }

    // bias
    float4 bv = *(const float4*)(bias + o0);
    #pragma unroll
    for (int p = 0; p < 4; ++p) {
        acc[p].x += bv.x; acc[p].y += bv.y; acc[p].z += bv.z; acc[p].w += bv.w;
    }

    if (LN) {
        float4 gv = *(const float4*)(g + o0);
        float4 bev = *(const float4*)(be + o0);
        #pragma unroll
        for (int p = 0; p < 4; ++p) {
            float s  = acc[p].x + acc[p].y + acc[p].z + acc[p].w;
            float ss = acc[p].x * acc[p].x + acc[p].y * acc[p].y
                     + acc[p].z * acc[p].z + acc[p].w * acc[p].w;
            #pragma unroll
            for (int off = 32; off; off >>= 1) {
                s  += __shfl_xor(s, off, 64);
                ss += __shfl_xor(ss, off, 64);
            }
            float mean = s * (1.f / 256.f);
            float var  = ss * (1.f / 256.f) - mean * mean;
            float rstd = rsqrtf(var + 1e-6f);
            float4 xn;
            xn.x = (acc[p].x - mean) * rstd * gv.x + bev.x;
            xn.y = (acc[p].y - mean) * rstd * gv.y + bev.y;
            xn.z = (acc[p].z - mean) * rstd * gv.z + bev.z;
            xn.w = (acc[p].w - mean) * rstd * gv.w + bev.w;
            if (SILU) {
                xn.x *= sigmoidf_(xn.x);
                xn.y *= sigmoidf_(xn.y);
                xn.z *= sigmoidf_(xn.z);
                xn.w *= sigmoidf_(xn.w);
            }
            acc[p] = xn;
        }
    }

    long qbase = q0 + pg * 4;
    if (OUT_CF) {
        #pragma unroll
        for (int p = 0; p < 4; ++p) {
            long q = qbase + p;
            size_t base = (size_t)((q >> 12) * C_) * HW + (q & 4095);
            y[base + (size_t)(o0 + 0) * HW] = acc[p].x;
            y[base + (size_t)(o0 + 1) * HW] = acc[p].y;
            y[base + (size_t)(o0 + 2) * HW] = acc[p].z;
            y[base + (size_t)(o0 + 3) * HW] = acc[p].w;
        }
    } else {
        #pragma unroll
        for (int p = 0; p < 4; ++p)
            *(float4*)(y + (qbase + p) * (size_t)C_ + o0) = acc[p];
    }
}

// ---------------------------------------------------------------- sim + softmax + spatial gaussian
// pxT: [B*HW][256]; ck0: [B*HW][49]
__global__ __launch_bounds__(256) void sim_k(const float* __restrict__ pxT,
                                             const float* __restrict__ sk,
                                             float* __restrict__ ck0)
{
    int t = threadIdx.x, lane = t & 63, wid = t >> 6;
    long q = (long)blockIdx.x * 4 + wid;
    int b = (int)(q >> 12), p = (int)(q & 4095), h = p >> 6, wcol = p & 63;
    const float4* px4 = (const float4*)pxT;
    float4 me = px4[q * 64 + lane];
    float mysim = -1e30f;
    #pragma unroll
    for (int n = 0; n < NN; ++n) {
        int hh = refl(h + n / 7 - 3), ww = refl(wcol + n % 7 - 3);
        long qn = ((long)b << 12) + hh * 64 + ww;
        float4 v = px4[qn * 64 + lane];
        float s = v.x * me.x + v.y * me.y + v.z * me.z + v.w * me.w;
        #pragma unroll
        for (int off = 32; off; off >>= 1) s += __shfl_xor(s, off, 64);
        if (lane == n) mysim = s * (1.f / 16.f);
    }
    float m = mysim;
    #pragma unroll
    for (int off = 32; off; off >>= 1) m = fmaxf(m, __shfl_xor(m, off, 64));
    float e = (lane < NN) ? __expf(mysim - m) : 0.f;
    float ssum = e;
    #pragma unroll
    for (int off = 32; off; off >>= 1) ssum += __shfl_xor(ssum, off, 64);
    if (lane < NN) ck0[q * NN + lane] = (e / ssum) * sk[lane];
}

// ---------------------------------------------------------------- fixup: conv(305->49)+LN+SiLU+conv(49->49)+gate+renorm
__global__ __launch_bounds__(256) void fixup_k(const float* __restrict__ ck0,
                                               const float* __restrict__ semT,
                                               const float* __restrict__ w1,
                                               const float* __restrict__ b1,
                                               const float* __restrict__ g,
                                               const float* __restrict__ be,
                                               const float* __restrict__ w2,
                                               const float* __restrict__ b2,
                                               float* __restrict__ ckn)
{
    __shared__ float hb[4][64];
    int t = threadIdx.x, lane = t & 63, wid = t >> 6;
    long q = (long)blockIdx.x * 4 + wid;
    int o = lane;
    float fx1 = 0.f;
    if (o < NN) {
        const float* wr = w1 + (size_t)o * KIN;
        const float* cr = ck0 + q * NN;
        for (int k = 0; k < NN; ++k) fx1 += wr[k] * cr[k];
        const float* sr = semT + q * (size_t)C_;
        for (int k = 0; k < C_; ++k) fx1 += wr[NN + k] * sr[k];
        fx1 += b1[o];
    }
    float v = (o < NN) ? fx1 : 0.f;
    float s = v, ss = v * v;
    #pragma unroll
    for (int off = 32; off; off >>= 1) {
        s  += __shfl_xor(s, off, 64);
        ss += __shfl_xor(ss, off, 64);
    }
    float mean = s * (1.f / 49.f);
    float var  = ss * (1.f / 49.f) - mean * mean;
    float rstd = rsqrtf(var + 1e-6f);
    float hv = 0.f;
    if (o < NN) {
        float xn = (fx1 - mean) * rstd * g[o] + be[o];
        hv = xn * sigmoidf_(xn);
    }
    hb[wid][lane] = hv;
    __syncthreads();
    float ckv = 0.f;
    if (o < NN) {
        float fx2 = b2[o];
        const float* w2r = w2 + (size_t)o * NN;
        for (int k = 0; k < NN; ++k) fx2 += w2r[k] * hb[wid][k];
        float c0 = ck0[q * NN + o];
        ckv = c0 * (1.f + sigmoidf_(fx2));
    }
    float tot = ckv;
    #pragma unroll
    for (int off = 32; off; off >>= 1) tot += __shfl_xor(tot, off, 64);
    if (o < NN) ckn[q * NN + o] = ckv / (tot + 1e-7f);
}

// ---------------------------------------------------------------- weighted neighborhood gather
__global__ __launch_bounds__(256) void gather_k(const float* __restrict__ spatT,
                                                const float* __restrict__ ckn,
                                                float* __restrict__ outT)
{
    int t = threadIdx.x, lane = t & 63, wid = t >> 6;
    long q = (long)blockIdx.x * 4 + wid;
    int b = (int)(q >> 12), p = (int)(q & 4095), h = p >> 6, wcol = p & 63;
    const float4* sp4 = (const float4*)spatT;
    const float* cr = ckn + q * NN;
    float4 acc = make_float4(0.f, 0.f, 0.f, 0.f);
    #pragma unroll
    for (int n = 0; n < NN; ++n) {
        int hh = refl(h + n / 7 - 3), ww = refl(wcol + n % 7 - 3);
        long qn = ((long)b << 12) + hh * 64 + ww;
        float cv = cr[n];
        float4 v = sp4[qn * 64 + lane];
        acc.x += cv * v.x; acc.y += cv * v.y; acc.z += cv * v.z; acc.w += cv * v.w;
    }
    ((float4*)outT)[q * 64 + lane] = acc;
}

// ---------------------------------------------------------------- launch
extern "C" void kernel_launch(void* const* d_in, const int* in_sizes, int n_in,
                              void* d_out, int out_size, void* d_ws, size_t ws_size,
                              hipStream_t stream)
{
    const float* spatial  = (const float*)d_in[0];
    const float* semantic = (const float*)d_in[1];
    const float* rp_w1 = (const float*)d_in[2];
    const float* rp_b1 = (const float*)d_in[3];
    const float* rp_g  = (const float*)d_in[4];
    const float* rp_be = (const float*)d_in[5];
    const float* rp_w2 = (const float*)d_in[6];
    const float* rp_b2 = (const float*)d_in[7];
    const float* fp_w1 = (const float*)d_in[8];
    const float* fp_b1 = (const float*)d_in[9];
    const float* fp_g  = (const float*)d_in[10];
    const float* fp_be = (const float*)d_in[11];
    const float* fp_w2 = (const float*)d_in[12];
    const float* fp_b2 = (const float*)d_in[13];
    const float* op_w1 = (const float*)d_in[14];
    const float* op_b1 = (const float*)d_in[15];
    const float* op_g  = (const float*)d_in[16];
    const float* op_be = (const float*)d_in[17];
    const float* op_w2 = (const float*)d_in[18];
    const float* op_b2 = (const float*)d_in[19];
    const float* sigma = (const float*)d_in[20];

    float* ws = (float*)d_ws;
    const size_t NPX = 2 * (size_t)HW;        // 8192 pixels
    float* sk   = ws;                          // 64
    float* spT  = sk + 64;                     // [8192][256]
    float* seT  = spT + NPX * C_;              // [8192][256]
    float* A    = seT + NPX * C_;              // [8192][256]
    float* Bt   = A   + NPX * C_;              // [8192][256]
    float* ck0  = Bt  + NPX * C_;              // [8192][49]
    float* ckn  = ck0 + NPX * NN;              // [8192][49]

    transpose_k<<<dim3(128, 8, 2), 256, 0, stream>>>(spatial,  spT, C_, HW);
    transpose_k<<<dim3(128, 8, 2), 256, 0, stream>>>(semantic, seT, C_, HW);
    sk_kernel<<<1, 64, 0, stream>>>(sigma, sk);

    // range_proj
    conv256_k<true,  true,  false><<<512, 256, 0, stream>>>(seT, rp_w1, rp_b1, rp_g, rp_be, A);
    conv256_k<false, false, false><<<512, 256, 0, stream>>>(A,   rp_w2, rp_b2, nullptr, nullptr, Bt);

    // similarity -> softmax -> * spatial gaussian
    sim_k<<<2048, 256, 0, stream>>>(Bt, sk, ck0);

    // fixup gate + renorm
    fixup_k<<<2048, 256, 0, stream>>>(ck0, seT, fp_w1, fp_b1, fp_g, fp_be, fp_w2, fp_b2, ckn);

    // weighted neighborhood sum
    gather_k<<<2048, 256, 0, stream>>>(spT, ckn, A);

    // output_proj (conv -> LN -> conv), last conv writes channel-first d_out
    conv256_k<true,  false, false><<<512, 256, 0, stream>>>(A,  op_w1, op_b1, op_g, op_be, Bt);
    conv256_k<false, false, true ><<<512, 256, 0, stream>>>(Bt, op_w2, op_b2, nullptr, nullptr, (float*)d_out);
}

// Round 2
// 184.068 us; speedup vs baseline: 1.2312x; 1.2312x over previous
//
#include <hip/hip_runtime.h>
#include <cmath>

#define HW 4096
#define C_ 256
#define NN 49
#define KW 305    // 49 + 256 (original w1 row length)
#define KP 320    // padded K: 64 (ck, 49 valid) + 256 (sem)

__device__ __forceinline__ int refl(int i) { return i < 0 ? -i : (i > 63 ? 126 - i : i); }
__device__ __forceinline__ float sigmoidf_(float x) { return 1.f / (1.f + __expf(-x)); }

// ---------------------------------------------------------------- transpose
// src: [B][R][Cc] -> dst: [B][Cc][R]
__global__ __launch_bounds__(256) void transpose_k(const float* __restrict__ src,
                                                   float* __restrict__ dst,
                                                   int R, int Cc)
{
    __shared__ float tile[32][33];
    int b = blockIdx.z;
    const float* s = src + (size_t)b * R * Cc;
    float* d = dst + (size_t)b * R * Cc;
    int c0 = blockIdx.x * 32, r0 = blockIdx.y * 32;
    int tx = threadIdx.x & 31, ty = threadIdx.x >> 5;   // 32 x 8
    #pragma unroll
    for (int i = 0; i < 32; i += 8)
        tile[ty + i][tx] = s[(size_t)(r0 + ty + i) * Cc + c0 + tx];
    __syncthreads();
    #pragma unroll
    for (int i = 0; i < 32; i += 8)
        d[(size_t)(c0 + ty + i) * R + r0 + tx] = tile[tx][ty + i];
}

// ---------------------------------------------------------------- spatial kernel
__global__ void sk_kernel(const float* __restrict__ sigma, float* __restrict__ sk)
{
    int n = threadIdx.x;
    if (n < NN) {
        int i = n / 7, j = n % 7;
        float xg = (i - 3) * (1.f / 3.f), yg = (j - 3) * (1.f / 3.f);
        float s = sigma[0];
        sk[n] = __expf(-(xg * xg + yg * yg) / (2.f * s * s));
    }
}

// ---------------------------------------------------------------- w1 transpose+pad prep
// w1Tp[kc][o] (kc<KP, o<64):
//   o<49:  kc<49 -> w1[o][kc]; 49<=kc<64 -> 0; kc>=64 -> w1[o][kc-15]
//   o>=49: 0
__global__ __launch_bounds__(256) void prep_w1T(const float* __restrict__ w1,
                                                float* __restrict__ w1Tp)
{
    int idx = blockIdx.x * 256 + threadIdx.x;
    if (idx >= KP * 64) return;
    int kc = idx >> 6, o = idx & 63;
    float v = 0.f;
    if (o < NN) {
        if (kc < NN) v = w1[o * KW + kc];
        else if (kc >= 64) v = w1[o * KW + (kc - 15)];
    }
    w1Tp[idx] = v;
}

// ---------------------------------------------------------------- fused conv1x1 (+LN (+SiLU))
template<bool LN, bool SILU, bool OUT_CF>
__global__ __launch_bounds__(256) void conv256_k(const float* __restrict__ xT,
                                                 const float* __restrict__ w,
                                                 const float* __restrict__ bias,
                                                 const float* __restrict__ g,
                                                 const float* __restrict__ be,
                                                 float* __restrict__ y)
{
    constexpr int PIX = 16, KC = 32;
    __shared__ __align__(16) float wl[KC][C_ + 4];   // [k][o], padded
    __shared__ __align__(16) float xl[KC][20];       // [k][p], padded
    int t = threadIdx.x;
    int wid = t >> 6;
    int o0 = (t & 63) * 4;
    int pg = wid;
    long q0 = (long)blockIdx.x * PIX;

    float4 acc[4];
    #pragma unroll
    for (int p = 0; p < 4; ++p) acc[p] = make_float4(0.f, 0.f, 0.f, 0.f);

    for (int kc = 0; kc < C_; kc += KC) {
        __syncthreads();
        {   // stage W chunk transposed: wl[k][o]
            int kk4 = (t & 7) * 4;
            int orow = t >> 3;
            #pragma unroll
            for (int it = 0; it < 8; ++it) {
                int oo = orow + it * 32;
                float4 wv = *(const float4*)(w + (size_t)oo * C_ + kc + kk4);
                wl[kk4 + 0][oo] = wv.x;
                wl[kk4 + 1][oo] = wv.y;
                wl[kk4 + 2][oo] = wv.z;
                wl[kk4 + 3][oo] = wv.w;
            }
        }
        {   // stage X chunk: xl[k][p]
            int p = t >> 4;
            int kk = (t & 15) * 2;
            float2 xv = *(const float2*)(xT + (q0 + p) * (size_t)C_ + kc + kk);
            xl[kk][p] = xv.x;
            xl[kk + 1][p] = xv.y;
        }
        __syncthreads();
        #pragma unroll
        for (int k = 0; k < KC; ++k) {
            float4 wv = *(const float4*)&wl[k][o0];
            float4 xv = *(const float4*)&xl[k][pg * 4];
            acc[0].x += wv.x * xv.x; acc[0].y += wv.y * xv.x; acc[0].z += wv.z * xv.x; acc[0].w += wv.w * xv.x;
            acc[1].x += wv.x * xv.y; acc[1].y += wv.y * xv.y; acc[1].z += wv.z * xv.y; acc[1].w += wv.w * xv.y;
            acc[2].x += wv.x * xv.z; acc[2].y += wv.y * xv.z; acc[2].z += wv.z * xv.z; acc[2].w += wv.w * xv.z;
            acc[3].x += wv.x * xv.w; acc[3].y += wv.y * xv.w; acc[3].z += wv.z * xv.w; acc[3].w += wv.w * xv.w;
        }
    }

    float4 bv = *(const float4*)(bias + o0);
    #pragma unroll
    for (int p = 0; p < 4; ++p) {
        acc[p].x += bv.x; acc[p].y += bv.y; acc[p].z += bv.z; acc[p].w += bv.w;
    }

    if (LN) {
        float4 gv = *(const float4*)(g + o0);
        float4 bev = *(const float4*)(be + o0);
        #pragma unroll
        for (int p = 0; p < 4; ++p) {
            float s  = acc[p].x + acc[p].y + acc[p].z + acc[p].w;
            float ss = acc[p].x * acc[p].x + acc[p].y * acc[p].y
                     + acc[p].z * acc[p].z + acc[p].w * acc[p].w;
            #pragma unroll
            for (int off = 32; off; off >>= 1) {
                s  += __shfl_xor(s, off, 64);
                ss += __shfl_xor(ss, off, 64);
            }
            float mean = s * (1.f / 256.f);
            float var  = ss * (1.f / 256.f) - mean * mean;
            float rstd = rsqrtf(var + 1e-6f);
            float4 xn;
            xn.x = (acc[p].x - mean) * rstd * gv.x + bev.x;
            xn.y = (acc[p].y - mean) * rstd * gv.y + bev.y;
            xn.z = (acc[p].z - mean) * rstd * gv.z + bev.z;
            xn.w = (acc[p].w - mean) * rstd * gv.w + bev.w;
            if (SILU) {
                xn.x *= sigmoidf_(xn.x);
                xn.y *= sigmoidf_(xn.y);
                xn.z *= sigmoidf_(xn.z);
                xn.w *= sigmoidf_(xn.w);
            }
            acc[p] = xn;
        }
    }

    long qbase = q0 + pg * 4;
    if (OUT_CF) {
        #pragma unroll
        for (int p = 0; p < 4; ++p) {
            long q = qbase + p;
            size_t base = (size_t)((q >> 12) * C_) * HW + (q & 4095);
            y[base + (size_t)(o0 + 0) * HW] = acc[p].x;
            y[base + (size_t)(o0 + 1) * HW] = acc[p].y;
            y[base + (size_t)(o0 + 2) * HW] = acc[p].z;
            y[base + (size_t)(o0 + 3) * HW] = acc[p].w;
        }
    } else {
        #pragma unroll
        for (int p = 0; p < 4; ++p)
            *(float4*)(y + (qbase + p) * (size_t)C_ + o0) = acc[p];
    }
}

// ---------------------------------------------------------------- sim + softmax + spatial gaussian
// pxT: [B*HW][256]; ckp: [B*HW][64] (lanes 49..63 zeroed)
__global__ __launch_bounds__(256) void sim_k(const float* __restrict__ pxT,
                                             const float* __restrict__ sk,
                                             float* __restrict__ ckp)
{
    int t = threadIdx.x, lane = t & 63, wid = t >> 6;
    long q = (long)blockIdx.x * 4 + wid;
    int b = (int)(q >> 12), p = (int)(q & 4095), h = p >> 6, wcol = p & 63;
    const float4* px4 = (const float4*)pxT;
    float4 me = px4[q * 64 + lane];
    float mysim = -1e30f;
    #pragma unroll
    for (int n = 0; n < NN; ++n) {
        int hh = refl(h + n / 7 - 3), ww = refl(wcol + n % 7 - 3);
        long qn = ((long)b << 12) + hh * 64 + ww;
        float4 v = px4[qn * 64 + lane];
        float s = v.x * me.x + v.y * me.y + v.z * me.z + v.w * me.w;
        #pragma unroll
        for (int off = 32; off; off >>= 1) s += __shfl_xor(s, off, 64);
        if (lane == n) mysim = s * (1.f / 16.f);
    }
    float m = mysim;
    #pragma unroll
    for (int off = 32; off; off >>= 1) m = fmaxf(m, __shfl_xor(m, off, 64));
    float e = (lane < NN) ? __expf(mysim - m) : 0.f;
    float ssum = e;
    #pragma unroll
    for (int off = 32; off; off >>= 1) ssum += __shfl_xor(ssum, off, 64);
    ckp[q * 64 + lane] = (lane < NN) ? (e / ssum) * sk[lane] : 0.f;
}

// ---------------------------------------------------------------- fixup GEMM: fx = W1p . [ckp|sem] + b1
// 16 pixels/block; thread: 1 output x 4 pixels. fx: [B*HW][64] (o>=49 are 0)
__global__ __launch_bounds__(256) void fixup_gemm(const float* __restrict__ ckp,
                                                  const float* __restrict__ semT,
                                                  const float* __restrict__ w1Tp,
                                                  const float* __restrict__ b1,
                                                  float* __restrict__ fx)
{
    constexpr int PIX = 16, KC = 32;
    __shared__ __align__(16) float wl[KC][64];
    __shared__ __align__(16) float xl[KC][20];
    int t = threadIdx.x;
    int o = t & 63, pg = t >> 6;
    long q0 = (long)blockIdx.x * PIX;

    float4 acc = make_float4(0.f, 0.f, 0.f, 0.f);

    for (int kc = 0; kc < KP; kc += KC) {
        __syncthreads();
        {   // stage W chunk: contiguous copy (w1Tp already [k][o])
            const float4* src = (const float4*)(w1Tp + (size_t)kc * 64 + t * 8);
            float4 a0 = src[0], a1 = src[1];
            int k = t >> 3, oo = (t & 7) * 8;
            *(float4*)&wl[k][oo] = a0;
            *(float4*)&wl[k][oo + 4] = a1;
        }
        {   // stage X chunk: xl[k][p]
            int p = t >> 4;
            int kk = (t & 15) * 2;
            float2 xv;
            if (kc < 64)
                xv = *(const float2*)(ckp + (q0 + p) * 64 + kc + kk);
            else
                xv = *(const float2*)(semT + (q0 + p) * (size_t)C_ + (kc - 64) + kk);
            xl[kk][p] = xv.x;
            xl[kk + 1][p] = xv.y;
        }
        __syncthreads();
        #pragma unroll
        for (int k = 0; k < KC; ++k) {
            float wv = wl[k][o];
            float4 xv = *(const float4*)&xl[k][pg * 4];
            acc.x += wv * xv.x;
            acc.y += wv * xv.y;
            acc.z += wv * xv.z;
            acc.w += wv * xv.w;
        }
    }
    float bv = (o < NN) ? b1[o] : 0.f;
    long qb = q0 + pg * 4;
    fx[(qb + 0) * 64 + o] = acc.x + bv;
    fx[(qb + 1) * 64 + o] = acc.y + bv;
    fx[(qb + 2) * 64 + o] = acc.z + bv;
    fx[(qb + 3) * 64 + o] = acc.w + bv;
}

// ---------------------------------------------------------------- fused fixup-post + gather
// per wave: one pixel. LN49+SiLU -> conv49 -> gate -> renorm -> weighted gather.
__global__ __launch_bounds__(256) void gather_fused(const float* __restrict__ spatT,
                                                    const float* __restrict__ ckp,
                                                    const float* __restrict__ fx,
                                                    const float* __restrict__ w2,
                                                    const float* __restrict__ b2,
                                                    const float* __restrict__ g,
                                                    const float* __restrict__ be,
                                                    float* __restrict__ outT)
{
    __shared__ float w2l[NN][51];   // stride 51 (odd) -> conflict-free column reads
    __shared__ float hb[4][64];
    int t = threadIdx.x, lane = t & 63, wid = t >> 6;
    long q = (long)blockIdx.x * 4 + wid;

    // stage w2
    for (int idx = t; idx < NN * NN; idx += 256)
        w2l[idx / NN][idx % NN] = w2[idx];

    // LN over 49 + SiLU
    float fxv = fx[q * 64 + lane];          // 0 for lane>=49
    float s = fxv, ss = fxv * fxv;
    #pragma unroll
    for (int off = 32; off; off >>= 1) {
        s  += __shfl_xor(s, off, 64);
        ss += __shfl_xor(ss, off, 64);
    }
    float mean = s * (1.f / 49.f);
    float var  = ss * (1.f / 49.f) - mean * mean;
    float rstd = rsqrtf(var + 1e-6f);
    float hv = 0.f;
    if (lane < NN) {
        float xn = (fxv - mean) * rstd * g[lane] + be[lane];
        hv = xn * sigmoidf_(xn);
    }
    hb[wid][lane] = hv;
    __syncthreads();   // covers w2l staging + hb visibility

    // conv49 + gate + renorm
    float ckv = 0.f;
    if (lane < NN) {
        float fx2 = b2[lane];
        #pragma unroll 7
        for (int k = 0; k < NN; ++k) fx2 += w2l[lane][k] * hb[wid][k];
        float c0 = ckp[q * 64 + lane];
        ckv = c0 * (1.f + sigmoidf_(fx2));
    }
    float tot = ckv;
    #pragma unroll
    for (int off = 32; off; off >>= 1) tot += __shfl_xor(tot, off, 64);
    float ckn = ckv / (tot + 1e-7f);
    __syncthreads();
    hb[wid][lane] = ckn;
    __syncthreads();

    // weighted neighborhood gather (lane = channel/4)
    int b = (int)(q >> 12), p = (int)(q & 4095), h = p >> 6, wcol = p & 63;
    const float4* sp4 = (const float4*)spatT;
    float4 acc = make_float4(0.f, 0.f, 0.f, 0.f);
    #pragma unroll
    for (int n = 0; n < NN; ++n) {
        int hh = refl(h + n / 7 - 3), ww = refl(wcol + n % 7 - 3);
        long qn = ((long)b << 12) + hh * 64 + ww;
        float cv = hb[wid][n];
        float4 v = sp4[qn * 64 + lane];
        acc.x += cv * v.x; acc.y += cv * v.y; acc.z += cv * v.z; acc.w += cv * v.w;
    }
    ((float4*)outT)[q * 64 + lane] = acc;
}

// ---------------------------------------------------------------- launch
extern "C" void kernel_launch(void* const* d_in, const int* in_sizes, int n_in,
                              void* d_out, int out_size, void* d_ws, size_t ws_size,
                              hipStream_t stream)
{
    const float* spatial  = (const float*)d_in[0];
    const float* semantic = (const float*)d_in[1];
    const float* rp_w1 = (const float*)d_in[2];
    const float* rp_b1 = (const float*)d_in[3];
    const float* rp_g  = (const float*)d_in[4];
    const float* rp_be = (const float*)d_in[5];
    const float* rp_w2 = (const float*)d_in[6];
    const float* rp_b2 = (const float*)d_in[7];
    const float* fp_w1 = (const float*)d_in[8];
    const float* fp_b1 = (const float*)d_in[9];
    const float* fp_g  = (const float*)d_in[10];
    const float* fp_be = (const float*)d_in[11];
    const float* fp_w2 = (const float*)d_in[12];
    const float* fp_b2 = (const float*)d_in[13];
    const float* op_w1 = (const float*)d_in[14];
    const float* op_b1 = (const float*)d_in[15];
    const float* op_g  = (const float*)d_in[16];
    const float* op_be = (const float*)d_in[17];
    const float* op_w2 = (const float*)d_in[18];
    const float* op_b2 = (const float*)d_in[19];
    const float* sigma = (const float*)d_in[20];

    float* ws = (float*)d_ws;
    const size_t NPX = 2 * (size_t)HW;        // 8192 pixels
    float* sk   = ws;                          // 64
    float* w1Tp = sk + 64;                     // 320*64
    float* spT  = w1Tp + (size_t)KP * 64;      // [8192][256]
    float* seT  = spT + NPX * C_;              // [8192][256]
    float* A    = seT + NPX * C_;              // [8192][256]  (also fx, also final LN out)
    float* Bt   = A   + NPX * C_;              // [8192][256]  (px, then gather out)
    float* ckp  = Bt  + NPX * C_;              // [8192][64]

    transpose_k<<<dim3(128, 8, 2), 256, 0, stream>>>(spatial,  spT, C_, HW);
    transpose_k<<<dim3(128, 8, 2), 256, 0, stream>>>(semantic, seT, C_, HW);
    sk_kernel<<<1, 64, 0, stream>>>(sigma, sk);
    prep_w1T<<<(KP * 64 + 255) / 256, 256, 0, stream>>>(fp_w1, w1Tp);

    // range_proj
    conv256_k<true,  true,  false><<<512, 256, 0, stream>>>(seT, rp_w1, rp_b1, rp_g, rp_be, A);
    conv256_k<false, false, false><<<512, 256, 0, stream>>>(A,   rp_w2, rp_b2, nullptr, nullptr, Bt);

    // similarity -> softmax -> * spatial gaussian
    sim_k<<<2048, 256, 0, stream>>>(Bt, sk, ckp);

    // fixup conv1 GEMM (fx aliases A)
    fixup_gemm<<<512, 256, 0, stream>>>(ckp, seT, w1Tp, fp_b1, A);

    // fixup post (LN+SiLU+conv49+gate+renorm) fused with gather -> Bt
    gather_fused<<<2048, 256, 0, stream>>>(spT, ckp, A, fp_w2, fp_b2, fp_g, fp_be, Bt);

    // output_proj (conv -> LN -> conv), last conv writes channel-first d_out
    conv256_k<true,  false, false><<<512, 256, 0, stream>>>(Bt, op_w1, op_b1, op_g, op_be, A);
    conv256_k<false, false, true ><<<512, 256, 0, stream>>>(A,  op_w2, op_b2, nullptr, nullptr, (float*)d_out);
}

// Round 3
// 123.874 us; speedup vs baseline: 1.8295x; 1.4859x over previous
//
#include <hip/hip_runtime.h>
#include <cstdint>

#define HW 4096
#define C_ 256
#define NN 49
#define KW 305    // 49 + 256 (original fixup w1 row length)
#define KP 320    // padded K: 64 (ck, 49 valid) + 256 (sem)

typedef __bf16 bf16;
typedef bf16 bf16x8 __attribute__((ext_vector_type(8)));
typedef bf16 bf16x4 __attribute__((ext_vector_type(4)));
typedef bf16 bf16x2 __attribute__((ext_vector_type(2)));
typedef float f32x4 __attribute__((ext_vector_type(4)));
typedef float f32x2 __attribute__((ext_vector_type(2)));

__device__ __forceinline__ int refl(int i) { return i < 0 ? -i : (i > 63 ? 126 - i : i); }
__device__ __forceinline__ float sigmoidf_(float x) { return 1.f / (1.f + __expf(-x)); }

// ---------------------------------------------------------------- fp32 [b][c][p] -> bf16 channel-last [b*HW+p][c]
__global__ __launch_bounds__(256) void cvtT_k(const float* __restrict__ src, bf16* __restrict__ dst)
{
    __shared__ float tile[32][33];
    int b = blockIdx.z;
    int p0 = blockIdx.x * 32, c0 = blockIdx.y * 32;
    int tx = threadIdx.x & 31, ty = threadIdx.x >> 5;
    const float* s = src + (size_t)b * C_ * HW;
    #pragma unroll
    for (int i = 0; i < 32; i += 8)
        tile[ty + i][tx] = s[(size_t)(c0 + ty + i) * HW + p0 + tx];
    __syncthreads();
    int p = threadIdx.x >> 3, cq = (threadIdx.x & 7) * 4;
    bf16x4 o = {(bf16)tile[cq][p], (bf16)tile[cq + 1][p], (bf16)tile[cq + 2][p], (bf16)tile[cq + 3][p]};
    *(bf16x4*)&dst[((size_t)b * HW + p0 + p) * C_ + c0 + cq] = o;
}

// ---------------------------------------------------------------- weight fp32 -> bf16 (flat 65536)
__global__ __launch_bounds__(256) void cvt_w(const float* __restrict__ src, bf16* __restrict__ dst)
{
    int i = (blockIdx.x * 256 + threadIdx.x) * 4;
    f32x4 v = *(const f32x4*)&src[i];
    bf16x4 o = {(bf16)v[0], (bf16)v[1], (bf16)v[2], (bf16)v[3]};
    *(bf16x4*)&dst[i] = o;
}

// ---------------------------------------------------------------- spatial gaussian
__global__ void sk_kernel(const float* __restrict__ sigma, float* __restrict__ sk)
{
    int n = threadIdx.x;
    if (n < NN) {
        int i = n / 7, j = n % 7;
        float xg = (i - 3) * (1.f / 3.f), yg = (j - 3) * (1.f / 3.f);
        float s = sigma[0];
        sk[n] = __expf(-(xg * xg + yg * yg) / (2.f * s * s));
    }
}

// ---------------------------------------------------------------- fixup w1 transpose+pad (fp32)
__global__ __launch_bounds__(256) void prep_w1T(const float* __restrict__ w1,
                                                float* __restrict__ w1Tp)
{
    int idx = blockIdx.x * 256 + threadIdx.x;
    if (idx >= KP * 64) return;
    int kc = idx >> 6, o = idx & 63;
    float v = 0.f;
    if (o < NN) {
        if (kc < NN) v = w1[o * KW + kc];
        else if (kc >= 64) v = w1[o * KW + (kc - 15)];
    }
    w1Tp[idx] = v;
}

// ---------------------------------------------------------------- MFMA bf16 conv1x1 (+bias)
// X: [8192][256] bf16 channel-last.  W: [256][256] bf16 row-major [o][k] (acts as B^T).
// MODE 0: Y bf16 [8192][256] channel-last (via LDS transpose epilogue)
// MODE 1: Y fp32 [B][256][4096] channel-first (final output)
template<int MODE>
__global__ __launch_bounds__(256) void mfma_conv(const bf16* __restrict__ X,
                                                 const bf16* __restrict__ W,
                                                 const float* __restrict__ bias,
                                                 void* __restrict__ Yv)
{
    __shared__ bf16 As[2][64 * 32];
    __shared__ bf16 Bs[2][64 * 32];
    const int t = threadIdx.x;
    const int lane = t & 63, wv = t >> 6;
    const int wr = wv >> 1, wc = wv & 1;        // wave tile origin (wr*32, wc*32)
    const int l15 = lane & 15, kb = lane >> 4;
    const long q0 = (long)blockIdx.x * 64;
    const int o0 = blockIdx.y * 64;

    // staging: thread t loads 16B; LDS dest linear t*16B = row(t>>2), slot(t&3)
    // source k-group pre-swizzled so that slot s holds data s ^ ((row>>1)&3)
    const int srow = t >> 2;
    const int kgd = (t & 3) ^ ((srow >> 1) & 3);
    const bf16* gA = X + (q0 + srow) * C_ + kgd * 8;
    const bf16* gB = W + (size_t)(o0 + srow) * C_ + kgd * 8;

    const float bo0 = bias[o0 + wc * 32 + l15];
    const float bo1 = bias[o0 + wc * 32 + 16 + l15];

    // frag-read offsets (swizzled): slot = kb ^ ((row>>1)&3); row base even*16 -> mask from l15 only
    const int mask = (l15 >> 1) & 3;
    const int kslot = (kb ^ mask) * 8;
    const int aoff0 = (wr * 32 + l15) * 32 + kslot;
    const int aoff1 = aoff0 + 16 * 32;
    const int boff0 = (wc * 32 + l15) * 32 + kslot;
    const int boff1 = boff0 + 16 * 32;

    f32x4 acc00 = {0.f, 0.f, 0.f, 0.f}, acc01 = {0.f, 0.f, 0.f, 0.f};
    f32x4 acc10 = {0.f, 0.f, 0.f, 0.f}, acc11 = {0.f, 0.f, 0.f, 0.f};

#define STAGE(bi, kc) do { \
    __builtin_amdgcn_global_load_lds((const __attribute__((address_space(1))) uint32_t*)(gA + (kc)), \
        (__attribute__((address_space(3))) uint32_t*)(&As[bi][t * 8]), 16, 0, 0); \
    __builtin_amdgcn_global_load_lds((const __attribute__((address_space(1))) uint32_t*)(gB + (kc)), \
        (__attribute__((address_space(3))) uint32_t*)(&Bs[bi][t * 8]), 16, 0, 0); \
} while (0)

    STAGE(0, 0);
    __syncthreads();
    int cur = 0;
    #pragma unroll
    for (int ks = 0; ks < 8; ++ks) {
        if (ks < 7) STAGE(cur ^ 1, (ks + 1) * 32);
        bf16x8 a0 = *(const bf16x8*)&As[cur][aoff0];
        bf16x8 a1 = *(const bf16x8*)&As[cur][aoff1];
        bf16x8 b0 = *(const bf16x8*)&Bs[cur][boff0];
        bf16x8 b1 = *(const bf16x8*)&Bs[cur][boff1];
        acc00 = __builtin_amdgcn_mfma_f32_16x16x32_bf16(a0, b0, acc00, 0, 0, 0);
        acc01 = __builtin_amdgcn_mfma_f32_16x16x32_bf16(a0, b1, acc01, 0, 0, 0);
        acc10 = __builtin_amdgcn_mfma_f32_16x16x32_bf16(a1, b0, acc10, 0, 0, 0);
        acc11 = __builtin_amdgcn_mfma_f32_16x16x32_bf16(a1, b1, acc11, 0, 0, 0);
        __syncthreads();
        cur ^= 1;
    }
#undef STAGE

    const int r4 = kb * 4;   // C/D: row = (lane>>4)*4 + reg, col = lane&15
    if constexpr (MODE == 0) {
        bf16* ost = &As[0][0];   // 64x64 bf16 = 8KB staging (As is free now)
        #pragma unroll
        for (int mn = 0; mn < 4; ++mn) {
            const int m = mn >> 1, n = mn & 1;
            const f32x4 av = (mn == 0) ? acc00 : (mn == 1) ? acc01 : (mn == 2) ? acc10 : acc11;
            const float bo = n ? bo1 : bo0;
            const int rr = wr * 32 + m * 16 + r4;
            const int cc = wc * 32 + n * 16 + l15;
            ost[(rr + 0) * 64 + cc] = (bf16)(av[0] + bo);
            ost[(rr + 1) * 64 + cc] = (bf16)(av[1] + bo);
            ost[(rr + 2) * 64 + cc] = (bf16)(av[2] + bo);
            ost[(rr + 3) * 64 + cc] = (bf16)(av[3] + bo);
        }
        __syncthreads();
        bf16* Y = (bf16*)Yv;
        const int p = t >> 2, cq = (t & 3) * 16;
        bf16x8 v0 = *(bf16x8*)&ost[p * 64 + cq];
        bf16x8 v1 = *(bf16x8*)&ost[p * 64 + cq + 8];
        *(bf16x8*)&Y[(q0 + p) * C_ + o0 + cq] = v0;
        *(bf16x8*)&Y[(q0 + p) * C_ + o0 + cq + 8] = v1;
    } else {
        float* Y = (float*)Yv;
        #pragma unroll
        for (int mn = 0; mn < 4; ++mn) {
            const int m = mn >> 1, n = mn & 1;
            const f32x4 av = (mn == 0) ? acc00 : (mn == 1) ? acc01 : (mn == 2) ? acc10 : acc11;
            const float bo = n ? bo1 : bo0;
            const long q = q0 + wr * 32 + m * 16 + r4;
            const int o = o0 + wc * 32 + n * 16 + l15;
            const int bb = (int)(q >> 12), pp = (int)(q & 4095);
            f32x4 val = {av[0] + bo, av[1] + bo, av[2] + bo, av[3] + bo};
            *(f32x4*)&Y[((size_t)bb * C_ + o) * HW + pp] = val;
        }
    }
}

// ---------------------------------------------------------------- LN over 256 ch (+ optional SiLU), bf16 -> bf16
template<bool SILU>
__global__ __launch_bounds__(256) void ln_k(const bf16* __restrict__ X,
                                            const float* __restrict__ g,
                                            const float* __restrict__ be,
                                            bf16* __restrict__ Y)
{
    int t = threadIdx.x, lane = t & 63, wv = t >> 6;
    long q = (long)blockIdx.x * 4 + wv;
    bf16x4 xv = *(const bf16x4*)&X[q * C_ + lane * 4];
    float x0 = xv[0], x1 = xv[1], x2 = xv[2], x3 = xv[3];
    float s = x0 + x1 + x2 + x3;
    float ss = x0 * x0 + x1 * x1 + x2 * x2 + x3 * x3;
    #pragma unroll
    for (int off = 32; off; off >>= 1) {
        s  += __shfl_xor(s, off, 64);
        ss += __shfl_xor(ss, off, 64);
    }
    float mean = s * (1.f / 256.f);
    float var  = ss * (1.f / 256.f) - mean * mean;
    float rstd = rsqrtf(var + 1e-6f);
    f32x4 gv = *(const f32x4*)&g[lane * 4];
    f32x4 bv = *(const f32x4*)&be[lane * 4];
    float y0 = (x0 - mean) * rstd * gv[0] + bv[0];
    float y1 = (x1 - mean) * rstd * gv[1] + bv[1];
    float y2 = (x2 - mean) * rstd * gv[2] + bv[2];
    float y3 = (x3 - mean) * rstd * gv[3] + bv[3];
    if (SILU) {
        y0 *= sigmoidf_(y0); y1 *= sigmoidf_(y1);
        y2 *= sigmoidf_(y2); y3 *= sigmoidf_(y3);
    }
    bf16x4 o = {(bf16)y0, (bf16)y1, (bf16)y2, (bf16)y3};
    *(bf16x4*)&Y[q * C_ + lane * 4] = o;
}

// ---------------------------------------------------------------- sim + softmax + spatial gaussian
// px: [8192][256] bf16; ckp: [8192][64] fp32 (lanes 49..63 zeroed)
__global__ __launch_bounds__(256) void sim_k(const bf16* __restrict__ px,
                                             const float* __restrict__ sk,
                                             float* __restrict__ ckp)
{
    int t = threadIdx.x, lane = t & 63, wid = t >> 6;
    long q = (long)blockIdx.x * 4 + wid;
    int b = (int)(q >> 12), p = (int)(q & 4095), h = p >> 6, wcol = p & 63;
    bf16x4 meb = *(const bf16x4*)&px[q * C_ + lane * 4];
    float m0 = meb[0], m1 = meb[1], m2 = meb[2], m3 = meb[3];
    float mysim = -1e30f;
    #pragma unroll
    for (int n = 0; n < NN; ++n) {
        int hh = refl(h + n / 7 - 3), ww = refl(wcol + n % 7 - 3);
        long qn = ((long)b << 12) + hh * 64 + ww;
        bf16x4 vb = *(const bf16x4*)&px[qn * C_ + lane * 4];
        float s = (float)vb[0] * m0 + (float)vb[1] * m1 + (float)vb[2] * m2 + (float)vb[3] * m3;
        #pragma unroll
        for (int off = 32; off; off >>= 1) s += __shfl_xor(s, off, 64);
        if (lane == n) mysim = s * (1.f / 16.f);
    }
    float mx = mysim;
    #pragma unroll
    for (int off = 32; off; off >>= 1) mx = fmaxf(mx, __shfl_xor(mx, off, 64));
    float e = (lane < NN) ? __expf(mysim - mx) : 0.f;
    float ssum = e;
    #pragma unroll
    for (int off = 32; off; off >>= 1) ssum += __shfl_xor(ssum, off, 64);
    ckp[q * 64 + lane] = (lane < NN) ? (e / ssum) * sk[lane] : 0.f;
}

// ---------------------------------------------------------------- fixup GEMM: fx = W1p . [ckp|sem] + b1 (fp32)
__global__ __launch_bounds__(256) void fixup_gemm(const float* __restrict__ ckp,
                                                  const bf16* __restrict__ seb,
                                                  const float* __restrict__ w1Tp,
                                                  const float* __restrict__ b1,
                                                  float* __restrict__ fx)
{
    constexpr int PIX = 16, KC = 32;
    __shared__ __align__(16) float wl[KC][64];
    __shared__ __align__(16) float xl[KC][20];
    int t = threadIdx.x;
    int o = t & 63, pg = t >> 6;
    long q0 = (long)blockIdx.x * PIX;

    f32x4 acc = {0.f, 0.f, 0.f, 0.f};

    for (int kc = 0; kc < KP; kc += KC) {
        __syncthreads();
        {
            const f32x4* src = (const f32x4*)(w1Tp + (size_t)kc * 64 + t * 8);
            f32x4 a0 = src[0], a1 = src[1];
            int k = t >> 3, oo = (t & 7) * 8;
            *(f32x4*)&wl[k][oo] = a0;
            *(f32x4*)&wl[k][oo + 4] = a1;
        }
        {
            int p = t >> 4;
            int kk = (t & 15) * 2;
            float xa, xb;
            if (kc < 64) {
                f32x2 xv = *(const f32x2*)(ckp + (q0 + p) * 64 + kc + kk);
                xa = xv[0]; xb = xv[1];
            } else {
                bf16x2 xv = *(const bf16x2*)(seb + (q0 + p) * (size_t)C_ + (kc - 64) + kk);
                xa = xv[0]; xb = xv[1];
            }
            xl[kk][p] = xa;
            xl[kk + 1][p] = xb;
        }
        __syncthreads();
        #pragma unroll
        for (int k = 0; k < KC; ++k) {
            float wv = wl[k][o];
            f32x4 xv = *(const f32x4*)&xl[k][pg * 4];
            acc[0] += wv * xv[0];
            acc[1] += wv * xv[1];
            acc[2] += wv * xv[2];
            acc[3] += wv * xv[3];
        }
    }
    float bv = (o < NN) ? b1[o] : 0.f;
    long qb = q0 + pg * 4;
    fx[(qb + 0) * 64 + o] = acc[0] + bv;
    fx[(qb + 1) * 64 + o] = acc[1] + bv;
    fx[(qb + 2) * 64 + o] = acc[2] + bv;
    fx[(qb + 3) * 64 + o] = acc[3] + bv;
}

// ---------------------------------------------------------------- fused fixup-post + gather
__global__ __launch_bounds__(256) void gather_fused(const bf16* __restrict__ spb,
                                                    const float* __restrict__ ckp,
                                                    const float* __restrict__ fx,
                                                    const float* __restrict__ w2,
                                                    const float* __restrict__ b2,
                                                    const float* __restrict__ g,
                                                    const float* __restrict__ be,
                                                    bf16* __restrict__ outb)
{
    __shared__ float w2l[NN][51];
    __shared__ float hb[4][64];
    int t = threadIdx.x, lane = t & 63, wid = t >> 6;
    long q = (long)blockIdx.x * 4 + wid;

    for (int idx = t; idx < NN * NN; idx += 256)
        w2l[idx / NN][idx % NN] = w2[idx];

    float fxv = fx[q * 64 + lane];
    float s = fxv, ss = fxv * fxv;
    #pragma unroll
    for (int off = 32; off; off >>= 1) {
        s  += __shfl_xor(s, off, 64);
        ss += __shfl_xor(ss, off, 64);
    }
    float mean = s * (1.f / 49.f);
    float var  = ss * (1.f / 49.f) - mean * mean;
    float rstd = rsqrtf(var + 1e-6f);
    float hv = 0.f;
    if (lane < NN) {
        float xn = (fxv - mean) * rstd * g[lane] + be[lane];
        hv = xn * sigmoidf_(xn);
    }
    hb[wid][lane] = hv;
    __syncthreads();

    float ckv = 0.f;
    if (lane < NN) {
        float fx2 = b2[lane];
        #pragma unroll 7
        for (int k = 0; k < NN; ++k) fx2 += w2l[lane][k] * hb[wid][k];
        float c0 = ckp[q * 64 + lane];
        ckv = c0 * (1.f + sigmoidf_(fx2));
    }
    float tot = ckv;
    #pragma unroll
    for (int off = 32; off; off >>= 1) tot += __shfl_xor(tot, off, 64);
    float ckn = ckv / (tot + 1e-7f);
    __syncthreads();
    hb[wid][lane] = ckn;
    __syncthreads();

    int b = (int)(q >> 12), p = (int)(q & 4095), h = p >> 6, wcol = p & 63;
    float a0 = 0.f, a1 = 0.f, a2 = 0.f, a3 = 0.f;
    #pragma unroll
    for (int n = 0; n < NN; ++n) {
        int hh = refl(h + n / 7 - 3), ww = refl(wcol + n % 7 - 3);
        long qn = ((long)b << 12) + hh * 64 + ww;
        float cv = hb[wid][n];
        bf16x4 v = *(const bf16x4*)&spb[qn * C_ + lane * 4];
        a0 += cv * (float)v[0]; a1 += cv * (float)v[1];
        a2 += cv * (float)v[2]; a3 += cv * (float)v[3];
    }
    bf16x4 o = {(bf16)a0, (bf16)a1, (bf16)a2, (bf16)a3};
    *(bf16x4*)&outb[q * C_ + lane * 4] = o;
}

// ---------------------------------------------------------------- launch
extern "C" void kernel_launch(void* const* d_in, const int* in_sizes, int n_in,
                              void* d_out, int out_size, void* d_ws, size_t ws_size,
                              hipStream_t stream)
{
    const float* spatial  = (const float*)d_in[0];
    const float* semantic = (const float*)d_in[1];
    const float* rp_w1 = (const float*)d_in[2];
    const float* rp_b1 = (const float*)d_in[3];
    const float* rp_g  = (const float*)d_in[4];
    const float* rp_be = (const float*)d_in[5];
    const float* rp_w2 = (const float*)d_in[6];
    const float* rp_b2 = (const float*)d_in[7];
    const float* fp_w1 = (const float*)d_in[8];
    const float* fp_b1 = (const float*)d_in[9];
    const float* fp_g  = (const float*)d_in[10];
    const float* fp_be = (const float*)d_in[11];
    const float* fp_w2 = (const float*)d_in[12];
    const float* fp_b2 = (const float*)d_in[13];
    const float* op_w1 = (const float*)d_in[14];
    const float* op_b1 = (const float*)d_in[15];
    const float* op_g  = (const float*)d_in[16];
    const float* op_be = (const float*)d_in[17];
    const float* op_w2 = (const float*)d_in[18];
    const float* op_b2 = (const float*)d_in[19];
    const float* sigma = (const float*)d_in[20];

    const size_t NPX = 2 * (size_t)HW;          // 8192 pixels
    float* ws = (float*)d_ws;
    float* sk   = ws;                            // 64
    float* w1Tp = sk + 64;                       // 320*64 = 20480
    float* ckp  = w1Tp + (size_t)KP * 64;        // 8192*64
    float* fx   = ckp + NPX * 64;                // 8192*64
    bf16* bfbase = (bf16*)(fx + NPX * 64);
    bf16* spb = bfbase;                          // [8192][256]
    bf16* seb = spb + NPX * C_;
    bf16* t0  = seb + NPX * C_;
    bf16* t1  = t0  + NPX * C_;
    bf16* wrp1 = t1 + NPX * C_;                  // 65536 each
    bf16* wrp2 = wrp1 + C_ * C_;
    bf16* wop1 = wrp2 + C_ * C_;
    bf16* wop2 = wop1 + C_ * C_;

    cvtT_k<<<dim3(128, 8, 2), 256, 0, stream>>>(spatial,  spb);
    cvtT_k<<<dim3(128, 8, 2), 256, 0, stream>>>(semantic, seb);
    sk_kernel<<<1, 64, 0, stream>>>(sigma, sk);
    prep_w1T<<<(KP * 64 + 255) / 256, 256, 0, stream>>>(fp_w1, w1Tp);
    cvt_w<<<64, 256, 0, stream>>>(rp_w1, wrp1);
    cvt_w<<<64, 256, 0, stream>>>(rp_w2, wrp2);
    cvt_w<<<64, 256, 0, stream>>>(op_w1, wop1);
    cvt_w<<<64, 256, 0, stream>>>(op_w2, wop2);

    // range_proj: conv -> LN+SiLU -> conv
    mfma_conv<0><<<dim3(128, 4), 256, 0, stream>>>(seb, wrp1, rp_b1, t0);
    ln_k<true><<<2048, 256, 0, stream>>>(t0, rp_g, rp_be, t1);
    mfma_conv<0><<<dim3(128, 4), 256, 0, stream>>>(t1, wrp2, rp_b2, t0);   // t0 = px

    // similarity -> softmax -> * spatial gaussian
    sim_k<<<2048, 256, 0, stream>>>(t0, sk, ckp);

    // fixup conv1 GEMM
    fixup_gemm<<<512, 256, 0, stream>>>(ckp, seb, w1Tp, fp_b1, fx);

    // fixup post + gather -> t1
    gather_fused<<<2048, 256, 0, stream>>>(spb, ckp, fx, fp_w2, fp_b2, fp_g, fp_be, t1);

    // output_proj: conv -> LN -> conv(final, fp32 channel-first)
    mfma_conv<0><<<dim3(128, 4), 256, 0, stream>>>(t1, wop1, op_b1, t0);
    ln_k<false><<<2048, 256, 0, stream>>>(t0, op_g, op_be, t1);
    mfma_conv<1><<<dim3(128, 4), 256, 0, stream>>>(t1, wop2, op_b2, d_out);
}

// Round 4
// 117.823 us; speedup vs baseline: 1.9234x; 1.0514x over previous
//
#include <hip/hip_runtime.h>
#include <cstdint>

#define HW 4096
#define C_ 256
#define NN 49
#define KW 305    // 49 + 256 (original fixup w1 row length)
#define KP 320    // padded K: 64 (ck, 49 valid) + 256 (sem)

typedef __bf16 bf16;
typedef bf16 bf16x8 __attribute__((ext_vector_type(8)));
typedef bf16 bf16x4 __attribute__((ext_vector_type(4)));
typedef bf16 bf16x2 __attribute__((ext_vector_type(2)));
typedef float f32x4 __attribute__((ext_vector_type(4)));
typedef float f32x2 __attribute__((ext_vector_type(2)));

__device__ __forceinline__ int refl(int i) { return i < 0 ? -i : (i > 63 ? 126 - i : i); }
__device__ __forceinline__ float sigmoidf_(float x) { return 1.f / (1.f + __expf(-x)); }

// ---------------------------------------------------------------- all weight prep in one launch
__global__ __launch_bounds__(256) void prep_all(const float* __restrict__ rp_w1,
                                                const float* __restrict__ rp_w2,
                                                const float* __restrict__ op_w1,
                                                const float* __restrict__ op_w2,
                                                const float* __restrict__ fp_w1,
                                                const float* __restrict__ sigma,
                                                bf16* __restrict__ wrp1, bf16* __restrict__ wrp2,
                                                bf16* __restrict__ wop1, bf16* __restrict__ wop2,
                                                float* __restrict__ w1Tp, float* __restrict__ sk)
{
    int bid = blockIdx.x;
    if (bid < 256) {
        const float* src = (bid < 64) ? rp_w1 : (bid < 128) ? rp_w2 : (bid < 192) ? op_w1 : op_w2;
        bf16* dst = (bid < 64) ? wrp1 : (bid < 128) ? wrp2 : (bid < 192) ? wop1 : wop2;
        int i = ((bid & 63) * 256 + threadIdx.x) * 4;
        f32x4 v = *(const f32x4*)&src[i];
        bf16x4 o = {(bf16)v[0], (bf16)v[1], (bf16)v[2], (bf16)v[3]};
        *(bf16x4*)&dst[i] = o;
    } else if (bid == 256) {
        int n = threadIdx.x;
        if (n < NN) {
            int i = n / 7, j = n % 7;
            float xg = (i - 3) * (1.f / 3.f), yg = (j - 3) * (1.f / 3.f);
            float s = sigma[0];
            sk[n] = __expf(-(xg * xg + yg * yg) / (2.f * s * s));
        }
    } else {
        int idx = (bid - 257) * 256 + threadIdx.x;
        if (idx < KP * 64) {
            int kc = idx >> 6, o = idx & 63;
            float v = 0.f;
            if (o < NN) {
                if (kc < NN) v = fp_w1[o * KW + kc];
                else if (kc >= 64) v = fp_w1[o * KW + (kc - 15)];
            }
            w1Tp[idx] = v;
        }
    }
}

// ---------------------------------------------------------------- fp32 [b][c][p] -> bf16 channel-last (both tensors)
__global__ __launch_bounds__(256) void cvtT_k(const float* __restrict__ spatial,
                                              const float* __restrict__ semantic,
                                              bf16* __restrict__ spb, bf16* __restrict__ seb)
{
    __shared__ float tile[32][33];
    int z = blockIdx.z;
    int b = z & 1;
    const float* src = (z >> 1) ? semantic : spatial;
    bf16* dst = (z >> 1) ? seb : spb;
    int p0 = blockIdx.x * 32, c0 = blockIdx.y * 32;
    int tx = threadIdx.x & 31, ty = threadIdx.x >> 5;
    const float* s = src + (size_t)b * C_ * HW;
    #pragma unroll
    for (int i = 0; i < 32; i += 8)
        tile[ty + i][tx] = s[(size_t)(c0 + ty + i) * HW + p0 + tx];
    __syncthreads();
    int p = threadIdx.x >> 3, cq = (threadIdx.x & 7) * 4;
    bf16x4 o = {(bf16)tile[cq][p], (bf16)tile[cq + 1][p], (bf16)tile[cq + 2][p], (bf16)tile[cq + 3][p]};
    *(bf16x4*)&dst[((size_t)b * HW + p0 + p) * C_ + c0 + cq] = o;
}

// ---------------------------------------------------------------- MFMA bf16 conv1x1 (+bias), optional LN(+SiLU) on INPUT
// X: [8192][256] bf16 channel-last.  W: [256][256] bf16 [o][k] (acts as B^T).
// LNIN: apply channel-LayerNorm (g,be) [+SiLU] to X inside the kernel before matmul.
// MODE 0: Y bf16 [8192][256] channel-last; MODE 1: Y fp32 [B][256][4096] channel-first.
template<bool LNIN, bool SILU, int MODE>
__global__ __launch_bounds__(256) void mfma_conv(const bf16* __restrict__ X,
                                                 const bf16* __restrict__ W,
                                                 const float* __restrict__ bias,
                                                 const float* __restrict__ g,
                                                 const float* __restrict__ be,
                                                 void* __restrict__ Yv)
{
    __shared__ bf16 Xf[64 * 256];      // 32KB, swizzled: 16B-slot ^= (row&7)
    __shared__ bf16 Bs[2][64 * 32];    // 8KB,  swizzled: slot(0..3) ^= ((row>>1)&3)
    const int t = threadIdx.x;
    const int lane = t & 63, wv = t >> 6;
    const int wr = wv >> 1, wc = wv & 1;
    const int l15 = lane & 15, kb = lane >> 4;
    const long q0 = (long)blockIdx.x * 64;
    const int o0 = blockIdx.y * 64;

    // ---- stage full X tile (64 rows x 256 ch), source pre-swizzled
    {
        const int srow = t >> 5;                 // 0..7 within each 8-row group
        const int sslot = (t & 31) ^ (srow & 7); // source k-group
        const bf16* gX = X + (q0 + srow) * C_ + sslot * 8;
        #pragma unroll
        for (int i = 0; i < 8; ++i)
            __builtin_amdgcn_global_load_lds((const __attribute__((address_space(1))) uint32_t*)(gX + (size_t)i * 8 * C_),
                (__attribute__((address_space(3))) uint32_t*)(&Xf[i * 2048 + t * 8]), 16, 0, 0);
    }
    // ---- B staging helper
    const int bsrow = t >> 2;
    const int bkgd = (t & 3) ^ ((t >> 3) & 3);
    const bf16* gB = W + (size_t)(o0 + bsrow) * C_ + bkgd * 8;
#define STAGE_B(bi, kc) \
    __builtin_amdgcn_global_load_lds((const __attribute__((address_space(1))) uint32_t*)(gB + (kc)), \
        (__attribute__((address_space(3))) uint32_t*)(&Bs[bi][t * 8]), 16, 0, 0)

    STAGE_B(0, 0);
    __syncthreads();

    if (LNIN) {
        // thread t: pixel p = t>>2, logical slots (t&3)*8 .. +7 (64 channels)
        const int p = t >> 2, sb = (t & 3) * 8;
        bf16x8 vals[8];
        float s = 0.f, ss = 0.f;
        #pragma unroll
        for (int j = 0; j < 8; ++j) {
            int slot = (sb + j) ^ (p & 7);
            vals[j] = *(const bf16x8*)&Xf[p * 256 + slot * 8];
            #pragma unroll
            for (int e = 0; e < 8; ++e) {
                float x = vals[j][e];
                s += x; ss += x * x;
            }
        }
        s  += __shfl_xor(s, 1, 64);  s  += __shfl_xor(s, 2, 64);
        ss += __shfl_xor(ss, 1, 64); ss += __shfl_xor(ss, 2, 64);
        float mean = s * (1.f / 256.f);
        float var  = ss * (1.f / 256.f) - mean * mean;
        float rstd = rsqrtf(var + 1e-6f);
        #pragma unroll
        for (int j = 0; j < 8; ++j) {
            int c = (sb + j) * 8;
            f32x4 g0 = *(const f32x4*)&g[c],  g1 = *(const f32x4*)&g[c + 4];
            f32x4 b0 = *(const f32x4*)&be[c], b1 = *(const f32x4*)&be[c + 4];
            bf16x8 o;
            #pragma unroll
            for (int e = 0; e < 8; ++e) {
                float gg = (e < 4) ? g0[e] : g1[e - 4];
                float bb = (e < 4) ? b0[e] : b1[e - 4];
                float y = ((float)vals[j][e] - mean) * rstd * gg + bb;
                if (SILU) y *= sigmoidf_(y);
                o[e] = (bf16)y;
            }
            int slot = (sb + j) ^ (p & 7);
            *(bf16x8*)&Xf[p * 256 + slot * 8] = o;
        }
        __syncthreads();
    }

    const float bo0 = bias[o0 + wc * 32 + l15];
    const float bo1 = bias[o0 + wc * 32 + 16 + l15];

    // frag-read offsets
    const int arow = (wr * 32 + l15) * 256;          // bf16 elems
    const int ax7 = l15 & 7;                         // (row&7), same for row and row+16
    const int bmask = (l15 >> 1) & 3;
    const int boff0 = (wc * 32 + l15) * 32 + (kb ^ bmask) * 8;
    const int boff1 = boff0 + 16 * 32;

    f32x4 acc00 = {0.f, 0.f, 0.f, 0.f}, acc01 = {0.f, 0.f, 0.f, 0.f};
    f32x4 acc10 = {0.f, 0.f, 0.f, 0.f}, acc11 = {0.f, 0.f, 0.f, 0.f};

    int cur = 0;
    #pragma unroll
    for (int ks = 0; ks < 8; ++ks) {
        if (ks < 7) STAGE_B(cur ^ 1, (ks + 1) * 32);
        const int kslot = ((ks * 4 + kb) ^ ax7) * 8;
        bf16x8 a0 = *(const bf16x8*)&Xf[arow + kslot];
        bf16x8 a1 = *(const bf16x8*)&Xf[arow + 16 * 256 + kslot];
        bf16x8 b0 = *(const bf16x8*)&Bs[cur][boff0];
        bf16x8 b1 = *(const bf16x8*)&Bs[cur][boff1];
        acc00 = __builtin_amdgcn_mfma_f32_16x16x32_bf16(a0, b0, acc00, 0, 0, 0);
        acc01 = __builtin_amdgcn_mfma_f32_16x16x32_bf16(a0, b1, acc01, 0, 0, 0);
        acc10 = __builtin_amdgcn_mfma_f32_16x16x32_bf16(a1, b0, acc10, 0, 0, 0);
        acc11 = __builtin_amdgcn_mfma_f32_16x16x32_bf16(a1, b1, acc11, 0, 0, 0);
        __syncthreads();
        cur ^= 1;
    }
#undef STAGE_B

    const int r4 = kb * 4;   // C/D: col = lane&15, row = (lane>>4)*4 + reg
    if constexpr (MODE == 0) {
        bf16* ost = &Bs[0][0];   // 64x64 bf16 = 8KB (Bs free after loop barrier)
        #pragma unroll
        for (int mn = 0; mn < 4; ++mn) {
            const int m = mn >> 1, n = mn & 1;
            const f32x4 av = (mn == 0) ? acc00 : (mn == 1) ? acc01 : (mn == 2) ? acc10 : acc11;
            const float bo = n ? bo1 : bo0;
            const int rr = wr * 32 + m * 16 + r4;
            const int cc = wc * 32 + n * 16 + l15;
            ost[(rr + 0) * 64 + cc] = (bf16)(av[0] + bo);
            ost[(rr + 1) * 64 + cc] = (bf16)(av[1] + bo);
            ost[(rr + 2) * 64 + cc] = (bf16)(av[2] + bo);
            ost[(rr + 3) * 64 + cc] = (bf16)(av[3] + bo);
        }
        __syncthreads();
        bf16* Y = (bf16*)Yv;
        const int p = t >> 2, cq = (t & 3) * 16;
        bf16x8 v0 = *(bf16x8*)&ost[p * 64 + cq];
        bf16x8 v1 = *(bf16x8*)&ost[p * 64 + cq + 8];
        *(bf16x8*)&Y[(q0 + p) * C_ + o0 + cq] = v0;
        *(bf16x8*)&Y[(q0 + p) * C_ + o0 + cq + 8] = v1;
    } else {
        float* Y = (float*)Yv;
        #pragma unroll
        for (int mn = 0; mn < 4; ++mn) {
            const int m = mn >> 1, n = mn & 1;
            const f32x4 av = (mn == 0) ? acc00 : (mn == 1) ? acc01 : (mn == 2) ? acc10 : acc11;
            const float bo = n ? bo1 : bo0;
            const long q = q0 + wr * 32 + m * 16 + r4;
            const int o = o0 + wc * 32 + n * 16 + l15;
            const int bb = (int)(q >> 12), pp = (int)(q & 4095);
            f32x4 val = {av[0] + bo, av[1] + bo, av[2] + bo, av[3] + bo};
            *(f32x4*)&Y[((size_t)bb * C_ + o) * HW + pp] = val;
        }
    }
}

// ---------------------------------------------------------------- sim + softmax + spatial gaussian
__global__ __launch_bounds__(256) void sim_k(const bf16* __restrict__ px,
                                             const float* __restrict__ sk,
                                             float* __restrict__ ckp)
{
    int t = threadIdx.x, lane = t & 63, wid = t >> 6;
    long q = (long)blockIdx.x * 4 + wid;
    int b = (int)(q >> 12), p = (int)(q & 4095), h = p >> 6, wcol = p & 63;
    bf16x4 meb = *(const bf16x4*)&px[q * C_ + lane * 4];
    float m0 = meb[0], m1 = meb[1], m2 = meb[2], m3 = meb[3];
    float mysim = -1e30f;
    #pragma unroll
    for (int n = 0; n < NN; ++n) {
        int hh = refl(h + n / 7 - 3), ww = refl(wcol + n % 7 - 3);
        long qn = ((long)b << 12) + hh * 64 + ww;
        bf16x4 vb = *(const bf16x4*)&px[qn * C_ + lane * 4];
        float s = (float)vb[0] * m0 + (float)vb[1] * m1 + (float)vb[2] * m2 + (float)vb[3] * m3;
        #pragma unroll
        for (int off = 32; off; off >>= 1) s += __shfl_xor(s, off, 64);
        if (lane == n) mysim = s * (1.f / 16.f);
    }
    float mx = mysim;
    #pragma unroll
    for (int off = 32; off; off >>= 1) mx = fmaxf(mx, __shfl_xor(mx, off, 64));
    float e = (lane < NN) ? __expf(mysim - mx) : 0.f;
    float ssum = e;
    #pragma unroll
    for (int off = 32; off; off >>= 1) ssum += __shfl_xor(ssum, off, 64);
    ckp[q * 64 + lane] = (lane < NN) ? (e / ssum) * sk[lane] : 0.f;
}

// ---------------------------------------------------------------- fused fixup GEMM + LN49 + conv49 + gate + renorm + gather
// 16 pixels per block (4 waves x 4 pixels).
__global__ __launch_bounds__(256) void fixgather(const bf16* __restrict__ spb,
                                                 const float* __restrict__ ckp,
                                                 const bf16* __restrict__ seb,
                                                 const float* __restrict__ w1Tp,
                                                 const float* __restrict__ b1,
                                                 const float* __restrict__ w2,
                                                 const float* __restrict__ b2,
                                                 const float* __restrict__ g,
                                                 const float* __restrict__ be,
                                                 bf16* __restrict__ outb)
{
    constexpr int KC = 32;
    __shared__ __align__(16) float wl[KC][64];
    __shared__ __align__(16) float xl[KC][20];
    __shared__ float w2l[NN][51];
    __shared__ float fxs[16][64];
    __shared__ float hb[4][64];
    int t = threadIdx.x, lane = t & 63, wid = t >> 6;
    int o = lane, pg = wid;
    long q0 = (long)blockIdx.x * 16;

    // stage w2 once (covered by phase-1 barriers)
    for (int idx = t; idx < NN * NN; idx += 256)
        w2l[idx / NN][idx % NN] = w2[idx];

    // ---- phase 1: fx = W1p . [ckp|sem] + b1  (16 pixels)
    f32x4 acc = {0.f, 0.f, 0.f, 0.f};
    for (int kc = 0; kc < KP; kc += KC) {
        __syncthreads();
        {
            const f32x4* src = (const f32x4*)(w1Tp + (size_t)kc * 64 + t * 8);
            f32x4 a0 = src[0], a1 = src[1];
            int k = t >> 3, oo = (t & 7) * 8;
            *(f32x4*)&wl[k][oo] = a0;
            *(f32x4*)&wl[k][oo + 4] = a1;
        }
        {
            int p = t >> 4;
            int kk = (t & 15) * 2;
            float xa, xb;
            if (kc < 64) {
                f32x2 xv = *(const f32x2*)(ckp + (q0 + p) * 64 + kc + kk);
                xa = xv[0]; xb = xv[1];
            } else {
                bf16x2 xv = *(const bf16x2*)(seb + (q0 + p) * (size_t)C_ + (kc - 64) + kk);
                xa = xv[0]; xb = xv[1];
            }
            xl[kk][p] = xa;
            xl[kk + 1][p] = xb;
        }
        __syncthreads();
        #pragma unroll
        for (int k = 0; k < KC; ++k) {
            float wv = wl[k][o];
            f32x4 xv = *(const f32x4*)&xl[k][pg * 4];
            acc[0] += wv * xv[0];
            acc[1] += wv * xv[1];
            acc[2] += wv * xv[2];
            acc[3] += wv * xv[3];
        }
    }
    float bv = (o < NN) ? b1[o] : 0.f;
    fxs[pg * 4 + 0][o] = acc[0] + bv;
    fxs[pg * 4 + 1][o] = acc[1] + bv;
    fxs[pg * 4 + 2][o] = acc[2] + bv;
    fxs[pg * 4 + 3][o] = acc[3] + bv;
    __syncthreads();   // w2l visible; fxs rows for this wave are wave-local anyway

    // ---- phase 2: per wave, 4 pixels sequentially
    float gl = (lane < NN) ? g[lane] : 0.f;
    float bel = (lane < NN) ? be[lane] : 0.f;
    float b2l = (lane < NN) ? b2[lane] : 0.f;
    for (int pp = 0; pp < 4; ++pp) {
        long q = q0 + wid * 4 + pp;
        float fxv = fxs[wid * 4 + pp][lane];   // 0 for lane>=49
        float s = fxv, ss = fxv * fxv;
        #pragma unroll
        for (int off = 32; off; off >>= 1) {
            s  += __shfl_xor(s, off, 64);
            ss += __shfl_xor(ss, off, 64);
        }
        float mean = s * (1.f / 49.f);
        float var  = ss * (1.f / 49.f) - mean * mean;
        float rstd = rsqrtf(var + 1e-6f);
        float hv = 0.f;
        if (lane < NN) {
            float xn = (fxv - mean) * rstd * gl + bel;
            hv = xn * sigmoidf_(xn);
        }
        hb[wid][lane] = hv;
        float ckv = 0.f;
        if (lane < NN) {
            float fx2 = b2l;
            #pragma unroll 7
            for (int k = 0; k < NN; ++k) fx2 += w2l[lane][k] * hb[wid][k];
            float c0 = ckp[q * 64 + lane];
            ckv = c0 * (1.f + sigmoidf_(fx2));
        }
        float tot = ckv;
        #pragma unroll
        for (int off = 32; off; off >>= 1) tot += __shfl_xor(tot, off, 64);
        hb[wid][lane] = ckv / (tot + 1e-7f);

        int b = (int)(q >> 12), p = (int)(q & 4095), h = p >> 6, wcol = p & 63;
        float a0 = 0.f, a1 = 0.f, a2 = 0.f, a3 = 0.f;
        #pragma unroll
        for (int n = 0; n < NN; ++n) {
            int hh = refl(h + n / 7 - 3), ww = refl(wcol + n % 7 - 3);
            long qn = ((long)b << 12) + hh * 64 + ww;
            float cv = hb[wid][n];
            bf16x4 v = *(const bf16x4*)&spb[qn * C_ + lane * 4];
            a0 += cv * (float)v[0]; a1 += cv * (float)v[1];
            a2 += cv * (float)v[2]; a3 += cv * (float)v[3];
        }
        bf16x4 ov = {(bf16)a0, (bf16)a1, (bf16)a2, (bf16)a3};
        *(bf16x4*)&outb[q * C_ + lane * 4] = ov;
    }
}

// ---------------------------------------------------------------- launch
extern "C" void kernel_launch(void* const* d_in, const int* in_sizes, int n_in,
                              void* d_out, int out_size, void* d_ws, size_t ws_size,
                              hipStream_t stream)
{
    const float* spatial  = (const float*)d_in[0];
    const float* semantic = (const float*)d_in[1];
    const float* rp_w1 = (const float*)d_in[2];
    const float* rp_b1 = (const float*)d_in[3];
    const float* rp_g  = (const float*)d_in[4];
    const float* rp_be = (const float*)d_in[5];
    const float* rp_w2 = (const float*)d_in[6];
    const float* rp_b2 = (const float*)d_in[7];
    const float* fp_w1 = (const float*)d_in[8];
    const float* fp_b1 = (const float*)d_in[9];
    const float* fp_g  = (const float*)d_in[10];
    const float* fp_be = (const float*)d_in[11];
    const float* fp_w2 = (const float*)d_in[12];
    const float* fp_b2 = (const float*)d_in[13];
    const float* op_w1 = (const float*)d_in[14];
    const float* op_b1 = (const float*)d_in[15];
    const float* op_g  = (const float*)d_in[16];
    const float* op_be = (const float*)d_in[17];
    const float* op_w2 = (const float*)d_in[18];
    const float* op_b2 = (const float*)d_in[19];
    const float* sigma = (const float*)d_in[20];

    const size_t NPX = 2 * (size_t)HW;          // 8192 pixels
    float* ws = (float*)d_ws;
    float* sk   = ws;                            // 64
    float* w1Tp = sk + 64;                       // 320*64
    float* ckp  = w1Tp + (size_t)KP * 64;        // 8192*64
    bf16* bfbase = (bf16*)(ckp + NPX * 64);
    bf16* spb = bfbase;                          // [8192][256]
    bf16* seb = spb + NPX * C_;
    bf16* t0  = seb + NPX * C_;
    bf16* t1  = t0  + NPX * C_;
    bf16* wrp1 = t1 + NPX * C_;
    bf16* wrp2 = wrp1 + C_ * C_;
    bf16* wop1 = wrp2 + C_ * C_;
    bf16* wop2 = wop1 + C_ * C_;

    prep_all<<<337, 256, 0, stream>>>(rp_w1, rp_w2, op_w1, op_w2, fp_w1, sigma,
                                      wrp1, wrp2, wop1, wop2, w1Tp, sk);
    cvtT_k<<<dim3(128, 8, 4), 256, 0, stream>>>(spatial, semantic, spb, seb);

    // range_proj: conv1 (+bias) -> conv2 with LN+SiLU on input
    mfma_conv<false, false, 0><<<dim3(128, 4), 256, 0, stream>>>(seb, wrp1, rp_b1, nullptr, nullptr, t0);
    mfma_conv<true,  true,  0><<<dim3(128, 4), 256, 0, stream>>>(t0, wrp2, rp_b2, rp_g, rp_be, t1);  // t1 = px

    // similarity -> softmax -> * spatial gaussian
    sim_k<<<2048, 256, 0, stream>>>(t1, sk, ckp);

    // fixup (GEMM + post) fused with gather -> t0
    fixgather<<<512, 256, 0, stream>>>(spb, ckp, seb, w1Tp, fp_b1, fp_w2, fp_b2, fp_g, fp_be, t0);

    // output_proj: conv1 (+bias) -> conv2 with LN on input, fp32 channel-first out
    mfma_conv<false, false, 0><<<dim3(128, 4), 256, 0, stream>>>(t0, wop1, op_b1, nullptr, nullptr, t1);
    mfma_conv<true,  false, 1><<<dim3(128, 4), 256, 0, stream>>>(t1, wop2, op_b2, op_g, op_be, d_out);
}

// Round 5
// 98.178 us; speedup vs baseline: 2.3083x; 1.2001x over previous
//
#include <hip/hip_runtime.h>
#include <cstdint>

#define HW 4096
#define C_ 256
#define NN 49
#define KW 305    // 49 + 256 (original fixup w1 row length)
#define KP 320    // padded K: 64 (ck, 49 valid) + 256 (sem)

typedef __bf16 bf16;
typedef bf16 bf16x8 __attribute__((ext_vector_type(8)));
typedef bf16 bf16x4 __attribute__((ext_vector_type(4)));
typedef bf16 bf16x2 __attribute__((ext_vector_type(2)));
typedef float f32x4 __attribute__((ext_vector_type(4)));
typedef float f32x2 __attribute__((ext_vector_type(2)));

__device__ __forceinline__ int refl(int i) { return i < 0 ? -i : (i > 63 ? 126 - i : i); }
__device__ __forceinline__ float sigmoidf_(float x) { return 1.f / (1.f + __expf(-x)); }

// ---------------------------------------------------------------- all weight prep in one launch
__global__ __launch_bounds__(256) void prep_all(const float* __restrict__ rp_w1,
                                                const float* __restrict__ rp_w2,
                                                const float* __restrict__ op_w1,
                                                const float* __restrict__ op_w2,
                                                const float* __restrict__ fp_w1,
                                                const float* __restrict__ sigma,
                                                bf16* __restrict__ wrp1, bf16* __restrict__ wrp2,
                                                bf16* __restrict__ wop1, bf16* __restrict__ wop2,
                                                float* __restrict__ w1Tp, float* __restrict__ sk)
{
    int bid = blockIdx.x;
    if (bid < 256) {
        const float* src = (bid < 64) ? rp_w1 : (bid < 128) ? rp_w2 : (bid < 192) ? op_w1 : op_w2;
        bf16* dst = (bid < 64) ? wrp1 : (bid < 128) ? wrp2 : (bid < 192) ? wop1 : wop2;
        int i = ((bid & 63) * 256 + threadIdx.x) * 4;
        f32x4 v = *(const f32x4*)&src[i];
        bf16x4 o = {(bf16)v[0], (bf16)v[1], (bf16)v[2], (bf16)v[3]};
        *(bf16x4*)&dst[i] = o;
    } else if (bid == 256) {
        int n = threadIdx.x;
        if (n < NN) {
            int i = n / 7, j = n % 7;
            float xg = (i - 3) * (1.f / 3.f), yg = (j - 3) * (1.f / 3.f);
            float s = sigma[0];
            sk[n] = __expf(-(xg * xg + yg * yg) / (2.f * s * s));
        }
    } else {
        int idx = (bid - 257) * 256 + threadIdx.x;
        if (idx < KP * 64) {
            int kc = idx >> 6, o = idx & 63;
            float v = 0.f;
            if (o < NN) {
                if (kc < NN) v = fp_w1[o * KW + kc];
                else if (kc >= 64) v = fp_w1[o * KW + (kc - 15)];
            }
            w1Tp[idx] = v;
        }
    }
}

// ---------------------------------------------------------------- fp32 [b][c][p] -> bf16 channel-last (both tensors)
__global__ __launch_bounds__(256) void cvtT_k(const float* __restrict__ spatial,
                                              const float* __restrict__ semantic,
                                              bf16* __restrict__ spb, bf16* __restrict__ seb)
{
    __shared__ float tile[32][33];
    int z = blockIdx.z;
    int b = z & 1;
    const float* src = (z >> 1) ? semantic : spatial;
    bf16* dst = (z >> 1) ? seb : spb;
    int p0 = blockIdx.x * 32, c0 = blockIdx.y * 32;
    int tx = threadIdx.x & 31, ty = threadIdx.x >> 5;
    const float* s = src + (size_t)b * C_ * HW;
    #pragma unroll
    for (int i = 0; i < 32; i += 8)
        tile[ty + i][tx] = s[(size_t)(c0 + ty + i) * HW + p0 + tx];
    __syncthreads();
    int p = threadIdx.x >> 3, cq = (threadIdx.x & 7) * 4;
    bf16x4 o = {(bf16)tile[cq][p], (bf16)tile[cq + 1][p], (bf16)tile[cq + 2][p], (bf16)tile[cq + 3][p]};
    *(bf16x4*)&dst[((size_t)b * HW + p0 + p) * C_ + c0 + cq] = o;
}

// ---------------------------------------------------------------- B-chunk staging: 256 out x 32 k, swizzled source
__device__ __forceinline__ void stage_b(const bf16* __restrict__ Wp, bf16* dst, int kc, int t)
{
    const bf16* gB = Wp + (size_t)(t >> 2) * C_ + kc + (((t & 3) ^ ((t >> 3) & 3)) * 8);
    #pragma unroll
    for (int ii = 0; ii < 4; ++ii)
        __builtin_amdgcn_global_load_lds((const __attribute__((address_space(1))) uint32_t*)(gB + (size_t)ii * 64 * C_),
            (__attribute__((address_space(3))) uint32_t*)(dst + ii * 2048 + t * 8), 16, 0, 0);
}

// ---------------------------------------------------------------- fused conv1x1 -> LN(+SiLU) -> conv1x1
// X: [8192][256] bf16 channel-last.  W1,W2: [256][256] bf16 [o][k].
// Block: 16 pixels x 256 outputs, 4 waves (each 16x64).
// MODE 0: Y bf16 [8192][256]; MODE 1: Y fp32 [B][256][4096].
template<bool SILU, int MODE>
__global__ __launch_bounds__(256) void conv_pair(const bf16* __restrict__ X,
                                                 const bf16* __restrict__ W1,
                                                 const float* __restrict__ b1v,
                                                 const float* __restrict__ g,
                                                 const float* __restrict__ be,
                                                 const bf16* __restrict__ W2,
                                                 const float* __restrict__ b2v,
                                                 void* __restrict__ Yv)
{
    __shared__ bf16 Xf[16 * 256];        // 8 KB input tile (row&7-swizzled 16B slots)
    __shared__ bf16 Mid[16 * 256];       // 8 KB normalized intermediate (same swizzle)
    __shared__ bf16 Bs[2][256 * 32];     // 32 KB W chunks ((o>>1)&3-swizzled slots)
    __shared__ float lnred[16][4][2];
    const int t = threadIdx.x;
    const int lane = t & 63, wc = t >> 6;    // wave = 64-col block
    const int l15 = lane & 15, kb = lane >> 4;
    const long q0 = (long)blockIdx.x * 16;

    // stage X (16 rows x 256 ch): dest linear, source slot ^= row&7
    {
        const int row = t >> 5, slot = t & 31;
        const bf16* gX = X + (q0 + row) * C_ + (slot ^ (row & 7)) * 8;
        __builtin_amdgcn_global_load_lds((const __attribute__((address_space(1))) uint32_t*)gX,
            (__attribute__((address_space(3))) uint32_t*)(&Xf[t * 8]), 16, 0, 0);
        __builtin_amdgcn_global_load_lds((const __attribute__((address_space(1))) uint32_t*)(gX + 8 * C_),
            (__attribute__((address_space(3))) uint32_t*)(&Xf[2048 + t * 8]), 16, 0, 0);
    }
    stage_b(W1, &Bs[0][0], 0, t);

    const int ax7 = l15 & 7;
    const int bsl = (kb ^ ((l15 >> 1) & 3)) * 8;
    int boff[4];
    #pragma unroll
    for (int n = 0; n < 4; ++n)
        boff[n] = (wc * 64 + n * 16 + l15) * 32 + bsl;

    f32x4 acc[4];
    #pragma unroll
    for (int n = 0; n < 4; ++n) acc[n] = (f32x4){0.f, 0.f, 0.f, 0.f};

    __syncthreads();
    int cur = 0;
    #pragma unroll
    for (int ks = 0; ks < 8; ++ks) {
        if (ks < 7) stage_b(W1, &Bs[cur ^ 1][0], (ks + 1) * 32, t);
        bf16x8 a = *(const bf16x8*)&Xf[l15 * 256 + ((ks * 4 + kb) ^ ax7) * 8];
        #pragma unroll
        for (int n = 0; n < 4; ++n) {
            bf16x8 b = *(const bf16x8*)&Bs[cur][boff[n]];
            acc[n] = __builtin_amdgcn_mfma_f32_16x16x32_bf16(a, b, acc[n], 0, 0, 0);
        }
        __syncthreads();
        cur ^= 1;
    }

    stage_b(W2, &Bs[0][0], 0, t);   // overlap with LN phase

    // bias1 + per-pixel LN partials (C/D: col=l15 -> channel, row=(kb*4+reg) -> pixel)
    float s4[4] = {0.f, 0.f, 0.f, 0.f}, ss4[4] = {0.f, 0.f, 0.f, 0.f};
    #pragma unroll
    for (int n = 0; n < 4; ++n) {
        float bo = b1v[wc * 64 + n * 16 + l15];
        #pragma unroll
        for (int r = 0; r < 4; ++r) {
            float v = acc[n][r] + bo;
            acc[n][r] = v;
            s4[r] += v; ss4[r] += v * v;
        }
    }
    #pragma unroll
    for (int off = 1; off <= 8; off <<= 1) {
        #pragma unroll
        for (int r = 0; r < 4; ++r) {
            s4[r]  += __shfl_xor(s4[r], off, 64);
            ss4[r] += __shfl_xor(ss4[r], off, 64);
        }
    }
    if (l15 == 0) {
        #pragma unroll
        for (int r = 0; r < 4; ++r) {
            lnred[kb * 4 + r][wc][0] = s4[r];
            lnred[kb * 4 + r][wc][1] = ss4[r];
        }
    }
    __syncthreads();
    float mean[4], rstd[4];
    #pragma unroll
    for (int r = 0; r < 4; ++r) {
        int p = kb * 4 + r;
        float st  = lnred[p][0][0] + lnred[p][1][0] + lnred[p][2][0] + lnred[p][3][0];
        float sst = lnred[p][0][1] + lnred[p][1][1] + lnred[p][2][1] + lnred[p][3][1];
        mean[r] = st * (1.f / 256.f);
        float var = sst * (1.f / 256.f) - mean[r] * mean[r];
        rstd[r] = rsqrtf(var + 1e-6f);
    }
    #pragma unroll
    for (int n = 0; n < 4; ++n) {
        int ch = wc * 64 + n * 16 + l15;
        float gv = g[ch], bev = be[ch];
        #pragma unroll
        for (int r = 0; r < 4; ++r) {
            float y = (acc[n][r] - mean[r]) * rstd[r] * gv + bev;
            if (SILU) y *= sigmoidf_(y);
            int p = kb * 4 + r;
            Mid[p * 256 + (((ch >> 3) ^ (p & 7)) * 8) + (ch & 7)] = (bf16)y;
        }
    }
    __syncthreads();   // Mid + B2 chunk0 ready

    f32x4 acc2[4];
    #pragma unroll
    for (int n = 0; n < 4; ++n) acc2[n] = (f32x4){0.f, 0.f, 0.f, 0.f};
    cur = 0;
    #pragma unroll
    for (int ks = 0; ks < 8; ++ks) {
        if (ks < 7) stage_b(W2, &Bs[cur ^ 1][0], (ks + 1) * 32, t);
        bf16x8 a = *(const bf16x8*)&Mid[l15 * 256 + ((ks * 4 + kb) ^ ax7) * 8];
        #pragma unroll
        for (int n = 0; n < 4; ++n) {
            bf16x8 b = *(const bf16x8*)&Bs[cur][boff[n]];
            acc2[n] = __builtin_amdgcn_mfma_f32_16x16x32_bf16(a, b, acc2[n], 0, 0, 0);
        }
        __syncthreads();
        cur ^= 1;
    }

    if constexpr (MODE == 0) {
        #pragma unroll
        for (int n = 0; n < 4; ++n) {
            int ch = wc * 64 + n * 16 + l15;
            float bo = b2v[ch];
            #pragma unroll
            for (int r = 0; r < 4; ++r)
                Xf[(kb * 4 + r) * 256 + ch] = (bf16)(acc2[n][r] + bo);
        }
        __syncthreads();
        bf16* Y = (bf16*)Yv;
        const int p = t >> 4, cb = (t & 15) * 16;
        bf16x8 v0 = *(const bf16x8*)&Xf[p * 256 + cb];
        bf16x8 v1 = *(const bf16x8*)&Xf[p * 256 + cb + 8];
        *(bf16x8*)&Y[(q0 + p) * C_ + cb] = v0;
        *(bf16x8*)&Y[(q0 + p) * C_ + cb + 8] = v1;
    } else {
        float* Y = (float*)Yv;
        const int bb = (int)(q0 >> 12);
        const int pp = (int)(q0 & 4095) + kb * 4;
        #pragma unroll
        for (int n = 0; n < 4; ++n) {
            int ch = wc * 64 + n * 16 + l15;
            float bo = b2v[ch];
            f32x4 val = {acc2[n][0] + bo, acc2[n][1] + bo, acc2[n][2] + bo, acc2[n][3] + bo};
            *(f32x4*)&Y[((size_t)bb * C_ + ch) * HW + pp] = val;
        }
    }
}

// ---------------------------------------------------------------- fused sim+softmax+fixup+gate+renorm+gather
// 16 pixels/block, 4 waves x 4 pixels.
__global__ __launch_bounds__(256) void attn_k(const bf16* __restrict__ px,
                                              const bf16* __restrict__ spb,
                                              const bf16* __restrict__ seb,
                                              const float* __restrict__ w1Tp,
                                              const float* __restrict__ b1,
                                              const float* __restrict__ w2,
                                              const float* __restrict__ b2,
                                              const float* __restrict__ g,
                                              const float* __restrict__ be,
                                              const float* __restrict__ sk,
                                              bf16* __restrict__ outb)
{
    __shared__ bf16 pxl[16 * 256];              // 8 KB own px rows
    __shared__ float ckl[16][64];               // 4 KB
    __shared__ float w2l[NN][51];               // ~10 KB
    __shared__ __align__(16) float wl[32][64];  // 8 KB
    __shared__ __align__(16) float xl[32][20];  // 2.5 KB
    __shared__ float hb[4][64];
    const int t = threadIdx.x, lane = t & 63, wid = t >> 6;
    const long q0 = (long)blockIdx.x * 16;

    // stage own px rows (linear dest, no swizzle needed: reads are broadcast)
    {
        const int row = t >> 5, slot = t & 31;
        const bf16* g0 = px + (q0 + row) * C_ + slot * 8;
        __builtin_amdgcn_global_load_lds((const __attribute__((address_space(1))) uint32_t*)g0,
            (__attribute__((address_space(3))) uint32_t*)(&pxl[t * 8]), 16, 0, 0);
        const bf16* g1 = px + (q0 + 8 + row) * C_ + slot * 8;
        __builtin_amdgcn_global_load_lds((const __attribute__((address_space(1))) uint32_t*)g1,
            (__attribute__((address_space(3))) uint32_t*)(&pxl[2048 + t * 8]), 16, 0, 0);
    }
    for (int idx = t; idx < NN * NN; idx += 256)
        w2l[idx / NN][idx % NN] = w2[idx];

    const float skv = (lane < NN) ? sk[lane] : 0.f;
    const int dy = (lane < NN) ? (lane / 7 - 3) : 0;
    const int dx = (lane < NN) ? (lane % 7 - 3) : 0;
    __syncthreads();

    // ---- sim + softmax: lane n = neighbor n, 4 pixels per wave
    #pragma unroll
    for (int j = 0; j < 4; ++j) {
        const int p = wid * 4 + j;
        const long q = q0 + p;
        const int b = (int)(q >> 12), pi = (int)(q & 4095);
        const int h = pi >> 6, wcol = pi & 63;
        const int hh = refl(h + dy), ww = refl(wcol + dx);
        const bf16* nbr = px + (((long)b << 12) + hh * 64 + ww) * C_;
        float d0 = 0.f, d1 = 0.f, d2 = 0.f, d3 = 0.f;
        #pragma unroll 8
        for (int i = 0; i < 32; ++i) {
            bf16x8 nb = *(const bf16x8*)&nbr[i * 8];
            bf16x8 ob = *(const bf16x8*)&pxl[p * 256 + i * 8];
            d0 += (float)nb[0] * (float)ob[0] + (float)nb[4] * (float)ob[4];
            d1 += (float)nb[1] * (float)ob[1] + (float)nb[5] * (float)ob[5];
            d2 += (float)nb[2] * (float)ob[2] + (float)nb[6] * (float)ob[6];
            d3 += (float)nb[3] * (float)ob[3] + (float)nb[7] * (float)ob[7];
        }
        float sim = ((d0 + d1) + (d2 + d3)) * (1.f / 16.f);
        float mx = (lane < NN) ? sim : -1e30f;
        #pragma unroll
        for (int off = 32; off; off >>= 1) mx = fmaxf(mx, __shfl_xor(mx, off, 64));
        float ev = (lane < NN) ? __expf(sim - mx) : 0.f;
        float ssum = ev;
        #pragma unroll
        for (int off = 32; off; off >>= 1) ssum += __shfl_xor(ssum, off, 64);
        ckl[p][lane] = (lane < NN) ? (ev / ssum) * skv : 0.f;
    }

    // ---- fixup GEMM: fx = W1p . [ck|sem] + b1 (acc in regs; o = lane, 4 pixels/wave)
    const int o = lane, pg = wid;
    f32x4 acc = {0.f, 0.f, 0.f, 0.f};
    for (int kc = 0; kc < KP; kc += 32) {
        __syncthreads();
        {
            const f32x4* src = (const f32x4*)(w1Tp + (size_t)kc * 64 + t * 8);
            f32x4 a0 = src[0], a1 = src[1];
            int k = t >> 3, oo = (t & 7) * 8;
            *(f32x4*)&wl[k][oo] = a0;
            *(f32x4*)&wl[k][oo + 4] = a1;
        }
        {
            int p = t >> 4;
            int kk = (t & 15) * 2;
            float xa, xb;
            if (kc < 64) {
                xa = ckl[p][kc + kk];
                xb = ckl[p][kc + kk + 1];
            } else {
                bf16x2 xv = *(const bf16x2*)&seb[(q0 + p) * (size_t)C_ + (kc - 64) + kk];
                xa = xv[0]; xb = xv[1];
            }
            xl[kk][p] = xa;
            xl[kk + 1][p] = xb;
        }
        __syncthreads();
        #pragma unroll
        for (int k = 0; k < 32; ++k) {
            float wv = wl[k][o];
            f32x4 xv = *(const f32x4*)&xl[k][pg * 4];
            acc[0] += wv * xv[0];
            acc[1] += wv * xv[1];
            acc[2] += wv * xv[2];
            acc[3] += wv * xv[3];
        }
    }
    float bv = (o < NN) ? b1[o] : 0.f;

    // ---- per-pixel: LN49+SiLU -> conv49 -> gate -> renorm -> gather
    float gl  = (lane < NN) ? g[lane] : 0.f;
    float bel = (lane < NN) ? be[lane] : 0.f;
    float b2l = (lane < NN) ? b2[lane] : 0.f;
    #pragma unroll
    for (int pp = 0; pp < 4; ++pp) {
        long q = q0 + wid * 4 + pp;
        float fxv = acc[pp] + bv;              // 0 for lane>=49 (w1Tp & bv zeroed)
        float s = fxv, ss = fxv * fxv;
        #pragma unroll
        for (int off = 32; off; off >>= 1) {
            s  += __shfl_xor(s, off, 64);
            ss += __shfl_xor(ss, off, 64);
        }
        float mean = s * (1.f / 49.f);
        float var  = ss * (1.f / 49.f) - mean * mean;
        float rstd = rsqrtf(var + 1e-6f);
        float hv = 0.f;
        if (lane < NN) {
            float xn = (fxv - mean) * rstd * gl + bel;
            hv = xn * sigmoidf_(xn);
        }
        hb[wid][lane] = hv;
        float ckv = 0.f;
        if (lane < NN) {
            float fx2 = b2l;
            #pragma unroll 7
            for (int k = 0; k < NN; ++k) fx2 += w2l[lane][k] * hb[wid][k];
            float c0 = ckl[wid * 4 + pp][lane];
            ckv = c0 * (1.f + sigmoidf_(fx2));
        }
        float tot = ckv;
        #pragma unroll
        for (int off = 32; off; off >>= 1) tot += __shfl_xor(tot, off, 64);
        hb[wid][lane] = ckv / (tot + 1e-7f);

        int b = (int)(q >> 12), pi = (int)(q & 4095), h = pi >> 6, wcol = pi & 63;
        float a0 = 0.f, a1 = 0.f, a2 = 0.f, a3 = 0.f;
        #pragma unroll
        for (int n = 0; n < NN; ++n) {
            int hh = refl(h + n / 7 - 3), ww = refl(wcol + n % 7 - 3);
            long qn = ((long)b << 12) + hh * 64 + ww;
            float cv = hb[wid][n];
            bf16x4 v = *(const bf16x4*)&spb[qn * C_ + lane * 4];
            a0 += cv * (float)v[0]; a1 += cv * (float)v[1];
            a2 += cv * (float)v[2]; a3 += cv * (float)v[3];
        }
        bf16x4 ov = {(bf16)a0, (bf16)a1, (bf16)a2, (bf16)a3};
        *(bf16x4*)&outb[q * C_ + lane * 4] = ov;
    }
}

// ---------------------------------------------------------------- launch
extern "C" void kernel_launch(void* const* d_in, const int* in_sizes, int n_in,
                              void* d_out, int out_size, void* d_ws, size_t ws_size,
                              hipStream_t stream)
{
    const float* spatial  = (const float*)d_in[0];
    const float* semantic = (const float*)d_in[1];
    const float* rp_w1 = (const float*)d_in[2];
    const float* rp_b1 = (const float*)d_in[3];
    const float* rp_g  = (const float*)d_in[4];
    const float* rp_be = (const float*)d_in[5];
    const float* rp_w2 = (const float*)d_in[6];
    const float* rp_b2 = (const float*)d_in[7];
    const float* fp_w1 = (const float*)d_in[8];
    const float* fp_b1 = (const float*)d_in[9];
    const float* fp_g  = (const float*)d_in[10];
    const float* fp_be = (const float*)d_in[11];
    const float* fp_w2 = (const float*)d_in[12];
    const float* fp_b2 = (const float*)d_in[13];
    const float* op_w1 = (const float*)d_in[14];
    const float* op_b1 = (const float*)d_in[15];
    const float* op_g  = (const float*)d_in[16];
    const float* op_be = (const float*)d_in[17];
    const float* op_w2 = (const float*)d_in[18];
    const float* op_b2 = (const float*)d_in[19];
    const float* sigma = (const float*)d_in[20];

    const size_t NPX = 2 * (size_t)HW;          // 8192 pixels
    float* ws = (float*)d_ws;
    float* sk   = ws;                            // 64
    float* w1Tp = sk + 64;                       // 320*64
    bf16* bfbase = (bf16*)(w1Tp + (size_t)KP * 64);
    bf16* spb = bfbase;                          // [8192][256]
    bf16* seb = spb + NPX * C_;
    bf16* t0  = seb + NPX * C_;
    bf16* t1  = t0  + NPX * C_;
    bf16* wrp1 = t1 + NPX * C_;
    bf16* wrp2 = wrp1 + C_ * C_;
    bf16* wop1 = wrp2 + C_ * C_;
    bf16* wop2 = wop1 + C_ * C_;

    prep_all<<<337, 256, 0, stream>>>(rp_w1, rp_w2, op_w1, op_w2, fp_w1, sigma,
                                      wrp1, wrp2, wop1, wop2, w1Tp, sk);
    cvtT_k<<<dim3(128, 8, 4), 256, 0, stream>>>(spatial, semantic, spb, seb);

    // range_proj fused pair: conv+bias -> LN+SiLU -> conv+bias  => t1 = px
    conv_pair<true, 0><<<512, 256, 0, stream>>>(seb, wrp1, rp_b1, rp_g, rp_be, wrp2, rp_b2, t1);

    // sim+softmax+fixup+gate+renorm+gather => t0
    attn_k<<<512, 256, 0, stream>>>(t1, spb, seb, w1Tp, fp_b1, fp_w2, fp_b2, fp_g, fp_be, sk, t0);

    // output_proj fused pair: conv+bias -> LN -> conv+bias, fp32 channel-first out
    conv_pair<false, 1><<<512, 256, 0, stream>>>(t0, wop1, op_b1, op_g, op_be, wop2, op_b2, d_out);
}

// Round 6
// 75.538 us; speedup vs baseline: 3.0002x; 1.2997x over previous
//
#include <hip/hip_runtime.h>
#include <cstdint>

#define HW 4096
#define C_ 256
#define NN 49
#define KW 305    // 49 + 256 (original fixup w1 row length)

typedef __bf16 bf16;
typedef bf16 bf16x8 __attribute__((ext_vector_type(8)));
typedef bf16 bf16x4 __attribute__((ext_vector_type(4)));
typedef bf16 bf16x2 __attribute__((ext_vector_type(2)));
typedef float f32x4 __attribute__((ext_vector_type(4)));

#define GLD16(src, dst) __builtin_amdgcn_global_load_lds( \
    (const __attribute__((address_space(1))) uint32_t*)(src), \
    (__attribute__((address_space(3))) uint32_t*)(dst), 16, 0, 0)

__device__ __forceinline__ int refl(int i) { return i < 0 ? -i : (i > 63 ? 126 - i : i); }
__device__ __forceinline__ float sigmoidf_(float x) { return 1.f / (1.f + __expf(-x)); }

// ---------------------------------------------------------------- all weight prep in one launch
// bid 0..255: 4x conv weights fp32->bf16; 256: spatial gaussian;
// 257..269: w1ck [k<49][o<64] fp32; 270..333: w1sem bf16 [64][256]
__global__ __launch_bounds__(256) void prep_all(const float* __restrict__ rp_w1,
                                                const float* __restrict__ rp_w2,
                                                const float* __restrict__ op_w1,
                                                const float* __restrict__ op_w2,
                                                const float* __restrict__ fp_w1,
                                                const float* __restrict__ sigma,
                                                bf16* __restrict__ wrp1, bf16* __restrict__ wrp2,
                                                bf16* __restrict__ wop1, bf16* __restrict__ wop2,
                                                float* __restrict__ w1ckg, bf16* __restrict__ w1sb,
                                                float* __restrict__ sk)
{
    int bid = blockIdx.x;
    if (bid < 256) {
        const float* src = (bid < 64) ? rp_w1 : (bid < 128) ? rp_w2 : (bid < 192) ? op_w1 : op_w2;
        bf16* dst = (bid < 64) ? wrp1 : (bid < 128) ? wrp2 : (bid < 192) ? wop1 : wop2;
        int i = ((bid & 63) * 256 + threadIdx.x) * 4;
        f32x4 v = *(const f32x4*)&src[i];
        bf16x4 o = {(bf16)v[0], (bf16)v[1], (bf16)v[2], (bf16)v[3]};
        *(bf16x4*)&dst[i] = o;
    } else if (bid == 256) {
        int n = threadIdx.x;
        if (n < NN) {
            int i = n / 7, j = n % 7;
            float xg = (i - 3) * (1.f / 3.f), yg = (j - 3) * (1.f / 3.f);
            float s = sigma[0];
            sk[n] = __expf(-(xg * xg + yg * yg) / (2.f * s * s));
        }
    } else if (bid < 270) {
        int idx = (bid - 257) * 256 + threadIdx.x;
        if (idx < NN * 64) {
            int k = idx >> 6, o = idx & 63;
            w1ckg[idx] = (o < NN) ? fp_w1[o * KW + k] : 0.f;
        }
    } else {
        int idx = (bid - 270) * 256 + threadIdx.x;   // < 16384
        int o = idx >> 8, c = idx & 255;
        w1sb[idx] = (o < NN) ? (bf16)fp_w1[o * KW + NN + c] : (bf16)0.f;
    }
}

// ---------------------------------------------------------------- fp32 [b][c][p] -> bf16 channel-last (both tensors)
__global__ __launch_bounds__(256) void cvtT_k(const float* __restrict__ spatial,
                                              const float* __restrict__ semantic,
                                              bf16* __restrict__ spb, bf16* __restrict__ seb)
{
    __shared__ float tile[32][33];
    int z = blockIdx.z;
    int b = z & 1;
    const float* src = (z >> 1) ? semantic : spatial;
    bf16* dst = (z >> 1) ? seb : spb;
    int p0 = blockIdx.x * 32, c0 = blockIdx.y * 32;
    int tx = threadIdx.x & 31, ty = threadIdx.x >> 5;
    const float* s = src + (size_t)b * C_ * HW;
    #pragma unroll
    for (int i = 0; i < 32; i += 8)
        tile[ty + i][tx] = s[(size_t)(c0 + ty + i) * HW + p0 + tx];
    __syncthreads();
    int p = threadIdx.x >> 3, cq = (threadIdx.x & 7) * 4;
    bf16x4 o = {(bf16)tile[cq][p], (bf16)tile[cq + 1][p], (bf16)tile[cq + 2][p], (bf16)tile[cq + 3][p]};
    *(bf16x4*)&dst[((size_t)b * HW + p0 + p) * C_ + c0 + cq] = o;
}

// ---------------------------------------------------------------- B-chunk staging: 256 out x 32 k, swizzled source
__device__ __forceinline__ void stage_b(const bf16* __restrict__ Wp, bf16* dst, int kc, int t)
{
    const bf16* gB = Wp + (size_t)(t >> 2) * C_ + kc + (((t & 3) ^ ((t >> 3) & 3)) * 8);
    #pragma unroll
    for (int ii = 0; ii < 4; ++ii)
        GLD16(gB + (size_t)ii * 64 * C_, dst + ii * 2048 + t * 8);
}

// ---------------------------------------------------------------- fused conv1x1 -> LN(+SiLU) -> conv1x1
template<bool SILU, int MODE>
__global__ __launch_bounds__(256) void conv_pair(const bf16* __restrict__ X,
                                                 const bf16* __restrict__ W1,
                                                 const float* __restrict__ b1v,
                                                 const float* __restrict__ g,
                                                 const float* __restrict__ be,
                                                 const bf16* __restrict__ W2,
                                                 const float* __restrict__ b2v,
                                                 void* __restrict__ Yv)
{
    __shared__ bf16 Xf[16 * 256];
    __shared__ bf16 Mid[16 * 256];
    __shared__ bf16 Bs[2][256 * 32];
    __shared__ float lnred[16][4][2];
    const int t = threadIdx.x;
    const int lane = t & 63, wc = t >> 6;
    const int l15 = lane & 15, kb = lane >> 4;
    const long q0 = (long)blockIdx.x * 16;

    {
        const int row = t >> 5, slot = t & 31;
        const bf16* gX = X + (q0 + row) * C_ + (slot ^ (row & 7)) * 8;
        GLD16(gX, &Xf[t * 8]);
        GLD16(gX + 8 * C_, &Xf[2048 + t * 8]);
    }
    stage_b(W1, &Bs[0][0], 0, t);

    const int ax7 = l15 & 7;
    const int bsl = (kb ^ ((l15 >> 1) & 3)) * 8;
    int boff[4];
    #pragma unroll
    for (int n = 0; n < 4; ++n)
        boff[n] = (wc * 64 + n * 16 + l15) * 32 + bsl;

    f32x4 acc[4];
    #pragma unroll
    for (int n = 0; n < 4; ++n) acc[n] = (f32x4){0.f, 0.f, 0.f, 0.f};

    __syncthreads();
    int cur = 0;
    #pragma unroll
    for (int ks = 0; ks < 8; ++ks) {
        if (ks < 7) stage_b(W1, &Bs[cur ^ 1][0], (ks + 1) * 32, t);
        bf16x8 a = *(const bf16x8*)&Xf[l15 * 256 + ((ks * 4 + kb) ^ ax7) * 8];
        #pragma unroll
        for (int n = 0; n < 4; ++n) {
            bf16x8 b = *(const bf16x8*)&Bs[cur][boff[n]];
            acc[n] = __builtin_amdgcn_mfma_f32_16x16x32_bf16(a, b, acc[n], 0, 0, 0);
        }
        __syncthreads();
        cur ^= 1;
    }

    stage_b(W2, &Bs[0][0], 0, t);

    float s4[4] = {0.f, 0.f, 0.f, 0.f}, ss4[4] = {0.f, 0.f, 0.f, 0.f};
    #pragma unroll
    for (int n = 0; n < 4; ++n) {
        float bo = b1v[wc * 64 + n * 16 + l15];
        #pragma unroll
        for (int r = 0; r < 4; ++r) {
            float v = acc[n][r] + bo;
            acc[n][r] = v;
            s4[r] += v; ss4[r] += v * v;
        }
    }
    #pragma unroll
    for (int off = 1; off <= 8; off <<= 1) {
        #pragma unroll
        for (int r = 0; r < 4; ++r) {
            s4[r]  += __shfl_xor(s4[r], off, 64);
            ss4[r] += __shfl_xor(ss4[r], off, 64);
        }
    }
    if (l15 == 0) {
        #pragma unroll
        for (int r = 0; r < 4; ++r) {
            lnred[kb * 4 + r][wc][0] = s4[r];
            lnred[kb * 4 + r][wc][1] = ss4[r];
        }
    }
    __syncthreads();
    float mean[4], rstd[4];
    #pragma unroll
    for (int r = 0; r < 4; ++r) {
        int p = kb * 4 + r;
        float st  = lnred[p][0][0] + lnred[p][1][0] + lnred[p][2][0] + lnred[p][3][0];
        float sst = lnred[p][0][1] + lnred[p][1][1] + lnred[p][2][1] + lnred[p][3][1];
        mean[r] = st * (1.f / 256.f);
        float var = sst * (1.f / 256.f) - mean[r] * mean[r];
        rstd[r] = rsqrtf(var + 1e-6f);
    }
    #pragma unroll
    for (int n = 0; n < 4; ++n) {
        int ch = wc * 64 + n * 16 + l15;
        float gv = g[ch], bev = be[ch];
        #pragma unroll
        for (int r = 0; r < 4; ++r) {
            float y = (acc[n][r] - mean[r]) * rstd[r] * gv + bev;
            if (SILU) y *= sigmoidf_(y);
            int p = kb * 4 + r;
            Mid[p * 256 + (((ch >> 3) ^ (p & 7)) * 8) + (ch & 7)] = (bf16)y;
        }
    }
    __syncthreads();

    f32x4 acc2[4];
    #pragma unroll
    for (int n = 0; n < 4; ++n) acc2[n] = (f32x4){0.f, 0.f, 0.f, 0.f};
    cur = 0;
    #pragma unroll
    for (int ks = 0; ks < 8; ++ks) {
        if (ks < 7) stage_b(W2, &Bs[cur ^ 1][0], (ks + 1) * 32, t);
        bf16x8 a = *(const bf16x8*)&Mid[l15 * 256 + ((ks * 4 + kb) ^ ax7) * 8];
        #pragma unroll
        for (int n = 0; n < 4; ++n) {
            bf16x8 b = *(const bf16x8*)&Bs[cur][boff[n]];
            acc2[n] = __builtin_amdgcn_mfma_f32_16x16x32_bf16(a, b, acc2[n], 0, 0, 0);
        }
        __syncthreads();
        cur ^= 1;
    }

    if constexpr (MODE == 0) {
        #pragma unroll
        for (int n = 0; n < 4; ++n) {
            int ch = wc * 64 + n * 16 + l15;
            float bo = b2v[ch];
            #pragma unroll
            for (int r = 0; r < 4; ++r)
                Xf[(kb * 4 + r) * 256 + ch] = (bf16)(acc2[n][r] + bo);
        }
        __syncthreads();
        bf16* Y = (bf16*)Yv;
        const int p = t >> 4, cb = (t & 15) * 16;
        bf16x8 v0 = *(const bf16x8*)&Xf[p * 256 + cb];
        bf16x8 v1 = *(const bf16x8*)&Xf[p * 256 + cb + 8];
        *(bf16x8*)&Y[(q0 + p) * C_ + cb] = v0;
        *(bf16x8*)&Y[(q0 + p) * C_ + cb + 8] = v1;
    } else {
        float* Y = (float*)Yv;
        const int bb = (int)(q0 >> 12);
        const int pp = (int)(q0 & 4095) + kb * 4;
        #pragma unroll
        for (int n = 0; n < 4; ++n) {
            int ch = wc * 64 + n * 16 + l15;
            float bo = b2v[ch];
            f32x4 val = {acc2[n][0] + bo, acc2[n][1] + bo, acc2[n][2] + bo, acc2[n][3] + bo};
            *(f32x4*)&Y[((size_t)bb * C_ + ch) * HW + pp] = val;
        }
    }
}

// ---------------------------------------------------------------- fused attn: MFMA sim + softmax + fixup + gate + gather
// block = 16 pixels (4x4 spatial tile); union of neighbors = 10x10 = 100 rows.
__global__ __launch_bounds__(256) void attn_k(const bf16* __restrict__ px,
                                              const bf16* __restrict__ spb,
                                              const bf16* __restrict__ seb,
                                              const bf16* __restrict__ w1sb,
                                              const float* __restrict__ w1ckg,
                                              const float* __restrict__ b1,
                                              const float* __restrict__ w2,
                                              const float* __restrict__ b2,
                                              const float* __restrict__ g,
                                              const float* __restrict__ be,
                                              const float* __restrict__ sk,
                                              bf16* __restrict__ outb)
{
    __shared__ float S[112 * 17];        // sim scores [u][p]
    __shared__ float fxs[64 * 17];       // fixup sem-part [o][p]
    __shared__ float w1ck[NN * 64];      // [k][o]
    __shared__ float w2l[NN][51];
    __shared__ float ckl[16][64];
    __shared__ float hb[4][64];
    __shared__ bf16 spatl[128 * 128];    // spat union c-chunk

    const int t = threadIdx.x, lane = t & 63, wid = t >> 6;
    const int l15 = lane & 15, kb = lane >> 4;
    const int blk = blockIdx.x;
    const int batch = blk >> 8, tt = blk & 255;
    const int h0 = (tt >> 4) * 4, w0 = (tt & 15) * 4;
    const long base = (long)batch * HW;

    // stage small weights
    #pragma unroll
    for (int i = 0; i < 13; ++i) {
        int idx = i * 256 + t;
        if (idx < NN * 64) w1ck[idx] = w1ckg[idx];
    }
    for (int idx = t; idx < NN * NN; idx += 256)
        w2l[idx / NN][idx % NN] = w2[idx];

    // ---- sim/fxsem MFMA: tiles 0..6 = px-union u-rows; 7..10 = w1sem o-rows
    const int ppy = l15 >> 2, ppx = l15 & 3;
    const long qB = base + (h0 + ppy) * 64 + (w0 + ppx);
    const bf16* bpxp = px + qB * C_ + kb * 8;
    const bf16* bsemp = seb + qB * C_ + kb * 8;

    bool valid[3], ispx[3];
    const bf16* arow[3];
    #pragma unroll
    for (int j = 0; j < 3; ++j) {
        int tid = wid + 4 * j;
        valid[j] = tid < 11;
        ispx[j] = tid < 7;
        int u = tid * 16 + l15;
        int uy = (u * 205) >> 11, ux = u - uy * 10;
        long grow = (u < 100) ? base + refl(h0 + uy - 3) * 64 + refl(w0 + ux - 3) : base;
        int o = (tid - 7) * 16 + l15;
        arow[j] = ispx[j] ? (px + grow * C_ + kb * 8)
                          : (w1sb + (size_t)(o & 63) * C_ + kb * 8);
    }

    f32x4 acc[3];
    #pragma unroll
    for (int j = 0; j < 3; ++j) acc[j] = (f32x4){0.f, 0.f, 0.f, 0.f};

    #pragma unroll
    for (int ks = 0; ks < 8; ++ks) {
        bf16x8 bp = *(const bf16x8*)(bpxp + ks * 32);
        bf16x8 bs = *(const bf16x8*)(bsemp + ks * 32);
        #pragma unroll
        for (int j = 0; j < 3; ++j) {
            if (valid[j]) {
                bf16x8 a = *(const bf16x8*)(arow[j] + ks * 32);
                acc[j] = __builtin_amdgcn_mfma_f32_16x16x32_bf16(a, ispx[j] ? bp : bs, acc[j], 0, 0, 0);
            }
        }
    }
    // write S / fxs   (C/D: col = l15 = p, rows = tile*16 + kb*4 + r)
    #pragma unroll
    for (int j = 0; j < 3; ++j) {
        if (valid[j]) {
            int tid = wid + 4 * j;
            float* dst = ispx[j] ? &S[(tid * 16 + kb * 4) * 17 + l15]
                                 : &fxs[((tid - 7) * 16 + kb * 4) * 17 + l15];
            dst[0] = acc[j][0]; dst[17] = acc[j][1]; dst[34] = acc[j][2]; dst[51] = acc[j][3];
        }
    }

    // ---- issue spat-union chunk0 staging (c 0..127), overlap with softmax/fixup
    const bf16* growp[8];
    {
        const int us = t >> 4, ss = t & 15;
        #pragma unroll
        for (int i = 0; i < 8; ++i) {
            int uu = i * 16 + us;
            int uy = (uu * 205) >> 11, ux = uu - uy * 10;
            long grow = (uu < 100) ? base + refl(h0 + uy - 3) * 64 + refl(w0 + ux - 3) : base;
            growp[i] = spb + grow * C_ + ss * 8;
            GLD16(growp[i], &spatl[uu * 128 + ss * 8]);
        }
    }
    __syncthreads();   // S, fxs, w1ck, w2l, spatl-chunk0 all ready

    // ---- softmax over 49 neighbors (wave -> 4 pixels)
    const float skv = (lane < NN) ? sk[lane] : 0.f;
    const int nn_ = (lane < NN) ? lane : 0;
    const int dy = nn_ / 7, dx = nn_ % 7;
    #pragma unroll
    for (int j = 0; j < 4; ++j) {
        int p = wid * 4 + j, py = p >> 2, px4 = p & 3;
        int u = (py + dy) * 10 + px4 + dx;
        float sval = (lane < NN) ? S[u * 17 + p] * 0.0625f : -1e30f;
        float mx = sval;
        #pragma unroll
        for (int off = 32; off; off >>= 1) mx = fmaxf(mx, __shfl_xor(mx, off, 64));
        float ev = (lane < NN) ? __expf(sval - mx) : 0.f;
        float ssum = ev;
        #pragma unroll
        for (int off = 32; off; off >>= 1) ssum += __shfl_xor(ssum, off, 64);
        ckl[p][lane] = (lane < NN) ? (ev / ssum) * skv : 0.f;
    }

    // ---- fixup-lite: fx = fxs + W1ck . ck + b1 -> LN49+SiLU -> conv49 -> gate -> renorm
    const float bo  = (lane < NN) ? b1[lane] : 0.f;
    const float gl  = (lane < NN) ? g[lane] : 0.f;
    const float bel = (lane < NN) ? be[lane] : 0.f;
    const float b2l = (lane < NN) ? b2[lane] : 0.f;
    #pragma unroll
    for (int j = 0; j < 4; ++j) {
        int p = wid * 4 + j;
        float fx = fxs[lane * 17 + p] + bo;
        #pragma unroll 7
        for (int k = 0; k < NN; ++k) fx += w1ck[k * 64 + lane] * ckl[p][k];
        float s = fx, ss = fx * fx;
        #pragma unroll
        for (int off = 32; off; off >>= 1) {
            s  += __shfl_xor(s, off, 64);
            ss += __shfl_xor(ss, off, 64);
        }
        float mean = s * (1.f / 49.f);
        float var  = ss * (1.f / 49.f) - mean * mean;
        float rstd = rsqrtf(var + 1e-6f);
        float hv = 0.f;
        if (lane < NN) {
            float xn = (fx - mean) * rstd * gl + bel;
            hv = xn * sigmoidf_(xn);
        }
        hb[wid][lane] = hv;
        float ckv = 0.f;
        if (lane < NN) {
            float fx2 = b2l;
            #pragma unroll 7
            for (int k = 0; k < NN; ++k) fx2 += w2l[lane][k] * hb[wid][k];
            ckv = ckl[p][lane] * (1.f + sigmoidf_(fx2));
        }
        float tot = ckv;
        #pragma unroll
        for (int off = 32; off; off >>= 1) tot += __shfl_xor(tot, off, 64);
        ckl[p][lane] = (lane < NN) ? ckv / (tot + 1e-7f) : 0.f;
    }

    // ---- gather from LDS spat union, 2 c-chunks of 128
    #pragma unroll
    for (int ci = 0; ci < 2; ++ci) {
        if (ci == 1) {
            __syncthreads();   // all waves done reading chunk0
            const int ss = t & 15;
            #pragma unroll
            for (int i = 0; i < 8; ++i) {
                int uu = i * 16 + (t >> 4);
                GLD16(growp[i] + 128, &spatl[uu * 128 + ss * 8]);
            }
            __syncthreads();   // chunk1 ready
        }
        #pragma unroll
        for (int j = 0; j < 4; ++j) {
            int p = wid * 4 + j, py = p >> 2, px4 = p & 3;
            long q = base + (h0 + py) * 64 + (w0 + px4);
            int ub = py * 10 + px4;
            float a0 = 0.f, a1 = 0.f;
            #pragma unroll
            for (int n = 0; n < NN; ++n) {
                int u = ub + (n / 7) * 10 + (n % 7);
                float cv = ckl[p][n];
                bf16x2 v = *(const bf16x2*)&spatl[u * 128 + lane * 2];
                a0 += cv * (float)v[0];
                a1 += cv * (float)v[1];
            }
            bf16x2 ov = {(bf16)a0, (bf16)a1};
            *(bf16x2*)&outb[q * C_ + ci * 128 + lane * 2] = ov;
        }
    }
}

// ---------------------------------------------------------------- launch
extern "C" void kernel_launch(void* const* d_in, const int* in_sizes, int n_in,
                              void* d_out, int out_size, void* d_ws, size_t ws_size,
                              hipStream_t stream)
{
    const float* spatial  = (const float*)d_in[0];
    const float* semantic = (const float*)d_in[1];
    const float* rp_w1 = (const float*)d_in[2];
    const float* rp_b1 = (const float*)d_in[3];
    const float* rp_g  = (const float*)d_in[4];
    const float* rp_be = (const float*)d_in[5];
    const float* rp_w2 = (const float*)d_in[6];
    const float* rp_b2 = (const float*)d_in[7];
    const float* fp_w1 = (const float*)d_in[8];
    const float* fp_b1 = (const float*)d_in[9];
    const float* fp_g  = (const float*)d_in[10];
    const float* fp_be = (const float*)d_in[11];
    const float* fp_w2 = (const float*)d_in[12];
    const float* fp_b2 = (const float*)d_in[13];
    const float* op_w1 = (const float*)d_in[14];
    const float* op_b1 = (const float*)d_in[15];
    const float* op_g  = (const float*)d_in[16];
    const float* op_be = (const float*)d_in[17];
    const float* op_w2 = (const float*)d_in[18];
    const float* op_b2 = (const float*)d_in[19];
    const float* sigma = (const float*)d_in[20];

    const size_t NPX = 2 * (size_t)HW;          // 8192 pixels
    float* ws = (float*)d_ws;
    float* sk    = ws;                           // 64
    float* w1ckg = sk + 64;                      // 49*64 = 3136 (pad to 3200)
    bf16* bfbase = (bf16*)(w1ckg + 3200);
    bf16* spb = bfbase;                          // [8192][256]
    bf16* seb = spb + NPX * C_;
    bf16* t0  = seb + NPX * C_;
    bf16* t1  = t0  + NPX * C_;
    bf16* wrp1 = t1 + NPX * C_;
    bf16* wrp2 = wrp1 + C_ * C_;
    bf16* wop1 = wrp2 + C_ * C_;
    bf16* wop2 = wop1 + C_ * C_;
    bf16* w1sb = wop2 + C_ * C_;                 // [64][256]

    prep_all<<<334, 256, 0, stream>>>(rp_w1, rp_w2, op_w1, op_w2, fp_w1, sigma,
                                      wrp1, wrp2, wop1, wop2, w1ckg, w1sb, sk);
    cvtT_k<<<dim3(128, 8, 4), 256, 0, stream>>>(spatial, semantic, spb, seb);

    // range_proj fused pair: conv+bias -> LN+SiLU -> conv+bias  => t1 = px
    conv_pair<true, 0><<<512, 256, 0, stream>>>(seb, wrp1, rp_b1, rp_g, rp_be, wrp2, rp_b2, t1);

    // sim(MFMA)+softmax+fixup+gate+renorm+gather => t0
    attn_k<<<512, 256, 0, stream>>>(t1, spb, seb, w1sb, w1ckg, fp_b1, fp_w2, fp_b2,
                                    fp_g, fp_be, sk, t0);

    // output_proj fused pair: conv+bias -> LN -> conv+bias, fp32 channel-first out
    conv_pair<false, 1><<<512, 256, 0, stream>>>(t0, wop1, op_b1, op_g, op_be, wop2, op_b2, d_out);
}

// Round 7
// 73.448 us; speedup vs baseline: 3.0855x; 1.0285x over previous
//
#include <hip/hip_runtime.h>
#include <cstdint>

#define HW 4096
#define C_ 256
#define NN 49
#define KW 305    // 49 + 256 (original fixup w1 row length)

typedef __bf16 bf16;
typedef bf16 bf16x8 __attribute__((ext_vector_type(8)));
typedef bf16 bf16x4 __attribute__((ext_vector_type(4)));
typedef bf16 bf16x2 __attribute__((ext_vector_type(2)));
typedef float f32x4 __attribute__((ext_vector_type(4)));

#define GLD16(src, dst) __builtin_amdgcn_global_load_lds( \
    (const __attribute__((address_space(1))) uint32_t*)(src), \
    (__attribute__((address_space(3))) uint32_t*)(dst), 16, 0, 0)

__device__ __forceinline__ int refl(int i) { return i < 0 ? -i : (i > 63 ? 126 - i : i); }
__device__ __forceinline__ float sigmoidf_(float x) { return 1.f / (1.f + __expf(-x)); }

// ---------------------------------------------------------------- setup: cvtT + all weight prep, one launch
// bid < 4096: fp32 [b][c][p] -> bf16 channel-last for spatial/semantic
// bid >= 4096: pid = bid-4096:
//   0..255 conv weights fp32->bf16; 256 gaussian; 257..269 w1ck f32 [49][64];
//   270..333 w1sem bf16 [64][256]; 334..346 w2T bf16 [49][64]
__global__ __launch_bounds__(256) void setup_k(const float* __restrict__ spatial,
                                               const float* __restrict__ semantic,
                                               const float* __restrict__ rp_w1,
                                               const float* __restrict__ rp_w2,
                                               const float* __restrict__ op_w1,
                                               const float* __restrict__ op_w2,
                                               const float* __restrict__ fp_w1,
                                               const float* __restrict__ fp_w2,
                                               const float* __restrict__ sigma,
                                               bf16* __restrict__ spb, bf16* __restrict__ seb,
                                               bf16* __restrict__ wrp1, bf16* __restrict__ wrp2,
                                               bf16* __restrict__ wop1, bf16* __restrict__ wop2,
                                               float* __restrict__ w1ckg, bf16* __restrict__ w1sb,
                                               bf16* __restrict__ w2Tg, float* __restrict__ sk)
{
    __shared__ float tile[32][33];
    const int bid = blockIdx.x, t = threadIdx.x;
    if (bid < 4096) {
        int z = bid >> 10, r = bid & 1023;
        int b = z & 1;
        const float* src = (z >> 1) ? semantic : spatial;
        bf16* dst = (z >> 1) ? seb : spb;
        int p0 = (r & 127) * 32, c0 = (r >> 7) * 32;
        int tx = t & 31, ty = t >> 5;
        const float* s = src + (size_t)b * C_ * HW;
        #pragma unroll
        for (int i = 0; i < 32; i += 8)
            tile[ty + i][tx] = s[(size_t)(c0 + ty + i) * HW + p0 + tx];
        __syncthreads();
        int p = t >> 3, cq = (t & 7) * 4;
        bf16x4 o = {(bf16)tile[cq][p], (bf16)tile[cq + 1][p], (bf16)tile[cq + 2][p], (bf16)tile[cq + 3][p]};
        *(bf16x4*)&dst[((size_t)b * HW + p0 + p) * C_ + c0 + cq] = o;
        return;
    }
    int pid = bid - 4096;
    if (pid < 256) {
        const float* src = (pid < 64) ? rp_w1 : (pid < 128) ? rp_w2 : (pid < 192) ? op_w1 : op_w2;
        bf16* dst = (pid < 64) ? wrp1 : (pid < 128) ? wrp2 : (pid < 192) ? wop1 : wop2;
        int i = ((pid & 63) * 256 + t) * 4;
        f32x4 v = *(const f32x4*)&src[i];
        bf16x4 o = {(bf16)v[0], (bf16)v[1], (bf16)v[2], (bf16)v[3]};
        *(bf16x4*)&dst[i] = o;
    } else if (pid == 256) {
        if (t < NN) {
            int i = t / 7, j = t % 7;
            float xg = (i - 3) * (1.f / 3.f), yg = (j - 3) * (1.f / 3.f);
            float s = sigma[0];
            sk[t] = __expf(-(xg * xg + yg * yg) / (2.f * s * s));
        }
    } else if (pid < 270) {
        int idx = (pid - 257) * 256 + t;
        if (idx < NN * 64) {
            int k = idx >> 6, o = idx & 63;
            w1ckg[idx] = (o < NN) ? fp_w1[o * KW + k] : 0.f;
        }
    } else if (pid < 334) {
        int idx = (pid - 270) * 256 + t;
        int o = idx >> 8, c = idx & 255;
        w1sb[idx] = (o < NN) ? (bf16)fp_w1[o * KW + NN + c] : (bf16)0.f;
    } else {
        int idx = (pid - 334) * 256 + t;
        if (idx < NN * 64) {
            int k = idx >> 6, o = idx & 63;
            w2Tg[idx] = (o < NN) ? (bf16)fp_w2[o * NN + k] : (bf16)0.f;
        }
    }
}

// ---------------------------------------------------------------- B-chunk staging: 256 out x 32 k, swizzled source
__device__ __forceinline__ void stage_b(const bf16* __restrict__ Wp, bf16* dst, int kc, int t)
{
    const bf16* gB = Wp + (size_t)(t >> 2) * C_ + kc + (((t & 3) ^ ((t >> 3) & 3)) * 8);
    #pragma unroll
    for (int ii = 0; ii < 4; ++ii)
        GLD16(gB + (size_t)ii * 64 * C_, dst + ii * 2048 + t * 8);
}

// ---------------------------------------------------------------- fused conv1x1 -> LN(+SiLU) -> conv1x1, 32 px/block
// X: [8192][256] bf16 channel-last.  W1,W2: [256][256] bf16 [o][k].
// MODE 0: Y bf16 [8192][256]; MODE 1: Y fp32 [B][256][4096].
template<bool SILU, int MODE>
__global__ __launch_bounds__(256) void conv_pair(const bf16* __restrict__ X,
                                                 const bf16* __restrict__ W1,
                                                 const float* __restrict__ b1v,
                                                 const float* __restrict__ g,
                                                 const float* __restrict__ be,
                                                 const bf16* __restrict__ W2,
                                                 const float* __restrict__ b2v,
                                                 void* __restrict__ Yv)
{
    __shared__ __align__(16) bf16 Xf[32 * 256];        // 16 KB (row&7-swizzled 16B slots)
    __shared__ __align__(16) bf16 Mid[32 * 256];       // 16 KB
    __shared__ __align__(16) bf16 Bs[2][256 * 32];     // 32 KB
    __shared__ float lnred[32][4][2];
    const int t = threadIdx.x;
    const int lane = t & 63, wc = t >> 6;
    const int l15 = lane & 15, kb = lane >> 4;
    const long q0 = (long)blockIdx.x * 32;

    // stage X (32 rows x 256 ch), source pre-swizzled
    {
        const int r8 = t >> 5, slot = t & 31;
        const bf16* gX = X + (q0 + r8) * C_ + ((slot ^ (r8 & 7)) * 8);
        #pragma unroll
        for (int i = 0; i < 4; ++i)
            GLD16(gX + (size_t)i * 8 * C_, &Xf[i * 2048 + t * 8]);
    }
    stage_b(W1, &Bs[0][0], 0, t);

    const int x7 = l15 & 7;
    const int bsl = (kb ^ ((l15 >> 1) & 3)) * 8;
    int boff[4];
    #pragma unroll
    for (int n = 0; n < 4; ++n)
        boff[n] = (wc * 64 + n * 16 + l15) * 32 + bsl;
    const int a0base = l15 * 256;
    const int a1base = (16 + l15) * 256;

    f32x4 acc[2][4];
    #pragma unroll
    for (int m = 0; m < 2; ++m)
        #pragma unroll
        for (int n = 0; n < 4; ++n) acc[m][n] = (f32x4){0.f, 0.f, 0.f, 0.f};

    __syncthreads();
    int cur = 0;
    #pragma unroll
    for (int ks = 0; ks < 8; ++ks) {
        if (ks < 7) stage_b(W1, &Bs[cur ^ 1][0], (ks + 1) * 32, t);
        const int ko = ((ks * 4 + kb) ^ x7) * 8;
        bf16x8 a0 = *(const bf16x8*)&Xf[a0base + ko];
        bf16x8 a1 = *(const bf16x8*)&Xf[a1base + ko];
        #pragma unroll
        for (int n = 0; n < 4; ++n) {
            bf16x8 b = *(const bf16x8*)&Bs[cur][boff[n]];
            acc[0][n] = __builtin_amdgcn_mfma_f32_16x16x32_bf16(a0, b, acc[0][n], 0, 0, 0);
            acc[1][n] = __builtin_amdgcn_mfma_f32_16x16x32_bf16(a1, b, acc[1][n], 0, 0, 0);
        }
        __syncthreads();
        cur ^= 1;
    }

    stage_b(W2, &Bs[0][0], 0, t);   // overlap with LN phase

    // bias1 + per-pixel LN partials. D: row = pixel (m*16 + kb*4 + r), col = ch (wc*64+n*16+l15)
    float s4[2][4], ss4[2][4];
    #pragma unroll
    for (int m = 0; m < 2; ++m)
        #pragma unroll
        for (int r = 0; r < 4; ++r) { s4[m][r] = 0.f; ss4[m][r] = 0.f; }
    #pragma unroll
    for (int n = 0; n < 4; ++n) {
        float bo = b1v[wc * 64 + n * 16 + l15];
        #pragma unroll
        for (int m = 0; m < 2; ++m)
            #pragma unroll
            for (int r = 0; r < 4; ++r) {
                float v = acc[m][n][r] + bo;
                acc[m][n][r] = v;
                s4[m][r] += v; ss4[m][r] += v * v;
            }
    }
    #pragma unroll
    for (int off = 1; off <= 8; off <<= 1)
        #pragma unroll
        for (int m = 0; m < 2; ++m)
            #pragma unroll
            for (int r = 0; r < 4; ++r) {
                s4[m][r]  += __shfl_xor(s4[m][r], off, 64);
                ss4[m][r] += __shfl_xor(ss4[m][r], off, 64);
            }
    if (l15 == 0) {
        #pragma unroll
        for (int m = 0; m < 2; ++m)
            #pragma unroll
            for (int r = 0; r < 4; ++r) {
                lnred[m * 16 + kb * 4 + r][wc][0] = s4[m][r];
                lnred[m * 16 + kb * 4 + r][wc][1] = ss4[m][r];
            }
    }
    __syncthreads();
    float mean[2][4], rstd[2][4];
    #pragma unroll
    for (int m = 0; m < 2; ++m)
        #pragma unroll
        for (int r = 0; r < 4; ++r) {
            int p = m * 16 + kb * 4 + r;
            float st  = lnred[p][0][0] + lnred[p][1][0] + lnred[p][2][0] + lnred[p][3][0];
            float sst = lnred[p][0][1] + lnred[p][1][1] + lnred[p][2][1] + lnred[p][3][1];
            mean[m][r] = st * (1.f / 256.f);
            float var = sst * (1.f / 256.f) - mean[m][r] * mean[m][r];
            rstd[m][r] = rsqrtf(var + 1e-6f);
        }
    #pragma unroll
    for (int n = 0; n < 4; ++n) {
        int ch = wc * 64 + n * 16 + l15;
        float gv = g[ch], bev = be[ch];
        #pragma unroll
        for (int m = 0; m < 2; ++m)
            #pragma unroll
            for (int r = 0; r < 4; ++r) {
                float y = (acc[m][n][r] - mean[m][r]) * rstd[m][r] * gv + bev;
                if (SILU) y *= sigmoidf_(y);
                int p = m * 16 + kb * 4 + r;
                Mid[p * 256 + (((ch >> 3) ^ (p & 7)) * 8) + (ch & 7)] = (bf16)y;
            }
    }
    __syncthreads();   // Mid + B2 chunk0 ready

    f32x4 acc2[2][4];
    #pragma unroll
    for (int m = 0; m < 2; ++m)
        #pragma unroll
        for (int n = 0; n < 4; ++n) acc2[m][n] = (f32x4){0.f, 0.f, 0.f, 0.f};
    cur = 0;
    #pragma unroll
    for (int ks = 0; ks < 8; ++ks) {
        if (ks < 7) stage_b(W2, &Bs[cur ^ 1][0], (ks + 1) * 32, t);
        const int ko = ((ks * 4 + kb) ^ x7) * 8;
        bf16x8 a0 = *(const bf16x8*)&Mid[a0base + ko];
        bf16x8 a1 = *(const bf16x8*)&Mid[a1base + ko];
        #pragma unroll
        for (int n = 0; n < 4; ++n) {
            bf16x8 b = *(const bf16x8*)&Bs[cur][boff[n]];
            acc2[0][n] = __builtin_amdgcn_mfma_f32_16x16x32_bf16(a0, b, acc2[0][n], 0, 0, 0);
            acc2[1][n] = __builtin_amdgcn_mfma_f32_16x16x32_bf16(a1, b, acc2[1][n], 0, 0, 0);
        }
        __syncthreads();
        cur ^= 1;
    }

    if constexpr (MODE == 0) {
        #pragma unroll
        for (int n = 0; n < 4; ++n) {
            int ch = wc * 64 + n * 16 + l15;
            float bo = b2v[ch];
            #pragma unroll
            for (int m = 0; m < 2; ++m)
                #pragma unroll
                for (int r = 0; r < 4; ++r)
                    Xf[(m * 16 + kb * 4 + r) * 256 + ch] = (bf16)(acc2[m][n][r] + bo);
        }
        __syncthreads();
        bf16* Y = (bf16*)Yv;
        const int p = t >> 3, cb = (t & 7) * 32;
        #pragma unroll
        for (int i = 0; i < 4; ++i) {
            bf16x8 v = *(const bf16x8*)&Xf[p * 256 + cb + i * 8];
            *(bf16x8*)&Y[(q0 + p) * C_ + cb + i * 8] = v;
        }
    } else {
        float* Y = (float*)Yv;
        const int bb = (int)(q0 >> 12);
        #pragma unroll
        for (int n = 0; n < 4; ++n) {
            int ch = wc * 64 + n * 16 + l15;
            float bo = b2v[ch];
            #pragma unroll
            for (int m = 0; m < 2; ++m) {
                int pp = (int)(q0 & 4095) + m * 16 + kb * 4;
                f32x4 val = {acc2[m][n][0] + bo, acc2[m][n][1] + bo,
                             acc2[m][n][2] + bo, acc2[m][n][3] + bo};
                *(f32x4*)&Y[((size_t)bb * C_ + ch) * HW + pp] = val;
            }
        }
    }
}

// ---------------------------------------------------------------- fused attn with LDS union buffer
// block = 16 pixels (4x4 tile); union = 10x10 = 100 rows (112 padded for MFMA tiles).
__global__ __launch_bounds__(256) void attn_k(const bf16* __restrict__ px,
                                              const bf16* __restrict__ spb,
                                              const bf16* __restrict__ seb,
                                              const bf16* __restrict__ w1sb,
                                              const float* __restrict__ w1ckg,
                                              const bf16* __restrict__ w2Tg,
                                              const float* __restrict__ b1,
                                              const float* __restrict__ b2,
                                              const float* __restrict__ g,
                                              const float* __restrict__ be,
                                              const float* __restrict__ sk,
                                              bf16* __restrict__ outb)
{
    __shared__ __align__(16) bf16 uni[112 * 256];   // 57344 B: px union, later spat union
    __shared__ float S[112 * 17];                   // 7616
    __shared__ float fxs[64 * 17];                  // 4352
    __shared__ __align__(16) bf16 w2lT[NN * 64];    // 6272: [k][o]
    __shared__ float ckl[16][64];                   // 4096
    __shared__ float hb[4][64];                     // 1024

    const int t = threadIdx.x, lane = t & 63, wid = t >> 6;
    const int l15 = lane & 15, kb = lane >> 4;
    const int blk = blockIdx.x;
    const int batch = blk >> 8, tt = blk & 255;
    const int h0 = (tt >> 4) * 4, w0 = (tt & 15) * 4;
    const long base = (long)batch * HW;

    // ---- stage px union (100 rows x 32 swizzled 16B slots) + w2T
    {
        #pragma unroll
        for (int i = 0; i < 13; ++i) {
            int st = i * 256 + t;
            if (st < 3200) {
                int u = st >> 5, s = st & 31;
                int uy = (u * 205) >> 11, ux = u - uy * 10;
                long grow = base + refl(h0 + uy - 3) * 64 + refl(w0 + ux - 3);
                GLD16(px + grow * C_ + ((s ^ (u & 7)) * 8), &uni[u * 256 + s * 8]);
            }
        }
        GLD16(w2Tg + t * 8, &w2lT[t * 8]);
        if (t < 136) GLD16(w2Tg + (256 + t) * 8, &w2lT[(256 + t) * 8]);
    }

    // ---- MFMA setup: tiles 0..6 sim (u-rows), 7..10 fxsem (w1sem rows x sem pixels)
    const int ppy = l15 >> 2, ppx = l15 & 3;
    const int u_p = 33 + ppy * 10 + ppx;
    const int bpbase = u_p * 256, bx7 = u_p & 7;
    const long qB = base + (h0 + ppy) * 64 + (w0 + ppx);
    const bf16* bsemp = seb + qB * C_ + kb * 8;
    const int x7 = l15 & 7;

    const int tid0 = wid, tid1 = wid + 4, tid2 = wid + 8;
    const bool t1sim = (tid1 < 7);           // wave 0..2: tile 4..6 sim; wave 3: tile 7 fxsem
    const bool t2valid = (tid2 < 11);        // waves 0..2: tiles 8..10 fxsem
    const int a0base = (tid0 * 16 + l15) * 256;
    const int a1base = (tid1 * 16 + l15) * 256;
    const bf16* a1g = w1sb + (size_t)(((tid1 - 7) & 3) * 16 + l15) * C_ + kb * 8;
    const bf16* a2g = w1sb + (size_t)(((tid2 - 7) & 3) * 16 + l15) * C_ + kb * 8;

    f32x4 acc0 = {0.f, 0.f, 0.f, 0.f}, acc1 = {0.f, 0.f, 0.f, 0.f}, acc2 = {0.f, 0.f, 0.f, 0.f};

    __syncthreads();   // uni + w2lT staged

    #pragma unroll
    for (int ks = 0; ks < 8; ++ks) {
        const int kg = ks * 4 + kb;
        bf16x8 bp = *(const bf16x8*)&uni[bpbase + ((kg ^ bx7) * 8)];
        bf16x8 a0 = *(const bf16x8*)&uni[a0base + ((kg ^ x7) * 8)];
        acc0 = __builtin_amdgcn_mfma_f32_16x16x32_bf16(a0, bp, acc0, 0, 0, 0);
        bf16x8 bs = *(const bf16x8*)(bsemp + ks * 32);
        bf16x8 a1;
        if (t1sim) a1 = *(const bf16x8*)&uni[a1base + ((kg ^ x7) * 8)];
        else       a1 = *(const bf16x8*)(a1g + ks * 32);
        acc1 = __builtin_amdgcn_mfma_f32_16x16x32_bf16(a1, t1sim ? bp : bs, acc1, 0, 0, 0);
        if (t2valid) {
            bf16x8 a2 = *(const bf16x8*)(a2g + ks * 32);
            acc2 = __builtin_amdgcn_mfma_f32_16x16x32_bf16(a2, bs, acc2, 0, 0, 0);
        }
    }
    // D: row = a-rows (u / o), col = b-rows (pixel)
    {
        float* dst = &S[(tid0 * 16 + kb * 4) * 17 + l15];
        dst[0] = acc0[0]; dst[17] = acc0[1]; dst[34] = acc0[2]; dst[51] = acc0[3];
    }
    if (t1sim) {
        float* dst = &S[(tid1 * 16 + kb * 4) * 17 + l15];
        dst[0] = acc1[0]; dst[17] = acc1[1]; dst[34] = acc1[2]; dst[51] = acc1[3];
    } else {
        float* dst = &fxs[(kb * 4) * 17 + l15];       // tile 7 -> fxs rows 0..15
        dst[0] = acc1[0]; dst[17] = acc1[1]; dst[34] = acc1[2]; dst[51] = acc1[3];
    }
    if (t2valid) {
        float* dst = &fxs[((tid2 - 7) * 16 + kb * 4) * 17 + l15];
        dst[0] = acc2[0]; dst[17] = acc2[1]; dst[34] = acc2[2]; dst[51] = acc2[3];
    }
    __syncthreads();   // S/fxs visible; all waves done reading px union

    // ---- issue spat union staging into uni (overlaps softmax + fixup)
    #pragma unroll
    for (int i = 0; i < 13; ++i) {
        int st = i * 256 + t;
        if (st < 3200) {
            int u = st >> 5, s = st & 31;
            int uy = (u * 205) >> 11, ux = u - uy * 10;
            long grow = base + refl(h0 + uy - 3) * 64 + refl(w0 + ux - 3);
            GLD16(spb + grow * C_ + ((s ^ (u & 7)) * 8), &uni[u * 256 + s * 8]);
        }
    }

    // hoist w1ck column (one coalesced read set)
    float w1r[NN];
    #pragma unroll
    for (int k = 0; k < NN; ++k) w1r[k] = w1ckg[k * 64 + lane];

    // ---- softmax over 49 neighbors (wave -> 4 pixels)
    const float skv = (lane < NN) ? sk[lane] : 0.f;
    const int nn_ = (lane < NN) ? lane : 0;
    const int dy = nn_ / 7, dx = nn_ % 7;
    #pragma unroll
    for (int j = 0; j < 4; ++j) {
        int p = wid * 4 + j, py = p >> 2, px4 = p & 3;
        int u = (py + dy) * 10 + px4 + dx;
        float sval = (lane < NN) ? S[u * 17 + p] * 0.0625f : -1e30f;
        float mx = sval;
        #pragma unroll
        for (int off = 32; off; off >>= 1) mx = fmaxf(mx, __shfl_xor(mx, off, 64));
        float ev = (lane < NN) ? __expf(sval - mx) : 0.f;
        float ssum = ev;
        #pragma unroll
        for (int off = 32; off; off >>= 1) ssum += __shfl_xor(ssum, off, 64);
        ckl[p][lane] = (lane < NN) ? (ev / ssum) * skv : 0.f;
    }

    // ---- fixup: fx = fxs + W1ck.ck + b1 -> LN49+SiLU -> conv49 -> gate -> renorm
    const float bo  = (lane < NN) ? b1[lane] : 0.f;
    const float gl  = (lane < NN) ? g[lane] : 0.f;
    const float bel = (lane < NN) ? be[lane] : 0.f;
    const float b2l = (lane < NN) ? b2[lane] : 0.f;
    #pragma unroll
    for (int j = 0; j < 4; ++j) {
        int p = wid * 4 + j;
        float fx = fxs[lane * 17 + p] + bo;
        #pragma unroll 7
        for (int k = 0; k < NN; ++k) fx += w1r[k] * ckl[p][k];
        float s = fx, ss = fx * fx;
        #pragma unroll
        for (int off = 32; off; off >>= 1) {
            s  += __shfl_xor(s, off, 64);
            ss += __shfl_xor(ss, off, 64);
        }
        float mean = s * (1.f / 49.f);
        float var  = ss * (1.f / 49.f) - mean * mean;
        float rstd = rsqrtf(var + 1e-6f);
        float hv = 0.f;
        if (lane < NN) {
            float xn = (fx - mean) * rstd * gl + bel;
            hv = xn * sigmoidf_(xn);
        }
        hb[wid][lane] = hv;
        float ckv = 0.f;
        if (lane < NN) {
            float fx2 = b2l;
            #pragma unroll 7
            for (int k = 0; k < NN; ++k) fx2 += (float)w2lT[k * 64 + lane] * hb[wid][k];
            ckv = ckl[p][lane] * (1.f + sigmoidf_(fx2));
        }
        float tot = ckv;
        #pragma unroll
        for (int off = 32; off; off >>= 1) tot += __shfl_xor(tot, off, 64);
        ckl[p][lane] = (lane < NN) ? ckv / (tot + 1e-7f) : 0.f;
    }
    __syncthreads();   // spat union staged (vmcnt drained) + ckl final

    // ---- gather: half-wave per pixel, full 256-ch bf16x8 reads
    const int hh_ = lane >> 5, l31 = lane & 31;
    #pragma unroll
    for (int jj = 0; jj < 2; ++jj) {
        int p = wid * 4 + jj * 2 + hh_;
        int py = p >> 2, px4 = p & 3;
        long q = base + (h0 + py) * 64 + (w0 + px4);
        int ub = py * 10 + px4;
        float a[8];
        #pragma unroll
        for (int e = 0; e < 8; ++e) a[e] = 0.f;
        for (int dyy = 0; dyy < 7; ++dyy) {
            #pragma unroll
            for (int dxx = 0; dxx < 7; ++dxx) {
                int u = ub + dyy * 10 + dxx;
                float cv = ckl[p][dyy * 7 + dxx];
                bf16x8 v = *(const bf16x8*)&uni[u * 256 + ((l31 ^ (u & 7)) * 8)];
                #pragma unroll
                for (int e = 0; e < 8; ++e) a[e] += cv * (float)v[e];
            }
        }
        bf16x8 ov;
        #pragma unroll
        for (int e = 0; e < 8; ++e) ov[e] = (bf16)a[e];
        *(bf16x8*)&outb[q * C_ + l31 * 8] = ov;
    }
}

// ---------------------------------------------------------------- launch
extern "C" void kernel_launch(void* const* d_in, const int* in_sizes, int n_in,
                              void* d_out, int out_size, void* d_ws, size_t ws_size,
                              hipStream_t stream)
{
    const float* spatial  = (const float*)d_in[0];
    const float* semantic = (const float*)d_in[1];
    const float* rp_w1 = (const float*)d_in[2];
    const float* rp_b1 = (const float*)d_in[3];
    const float* rp_g  = (const float*)d_in[4];
    const float* rp_be = (const float*)d_in[5];
    const float* rp_w2 = (const float*)d_in[6];
    const float* rp_b2 = (const float*)d_in[7];
    const float* fp_w1 = (const float*)d_in[8];
    const float* fp_b1 = (const float*)d_in[9];
    const float* fp_g  = (const float*)d_in[10];
    const float* fp_be = (const float*)d_in[11];
    const float* fp_w2 = (const float*)d_in[12];
    const float* fp_b2 = (const float*)d_in[13];
    const float* op_w1 = (const float*)d_in[14];
    const float* op_b1 = (const float*)d_in[15];
    const float* op_g  = (const float*)d_in[16];
    const float* op_be = (const float*)d_in[17];
    const float* op_w2 = (const float*)d_in[18];
    const float* op_b2 = (const float*)d_in[19];
    const float* sigma = (const float*)d_in[20];

    const size_t NPX = 2 * (size_t)HW;          // 8192 pixels
    float* ws = (float*)d_ws;
    float* sk    = ws;                           // 64
    float* w1ckg = sk + 64;                      // 3200
    bf16* bfbase = (bf16*)(w1ckg + 3200);
    bf16* spb = bfbase;                          // [8192][256]
    bf16* seb = spb + NPX * C_;
    bf16* t0  = seb + NPX * C_;
    bf16* t1  = t0  + NPX * C_;
    bf16* wrp1 = t1 + NPX * C_;
    bf16* wrp2 = wrp1 + C_ * C_;
    bf16* wop1 = wrp2 + C_ * C_;
    bf16* wop2 = wop1 + C_ * C_;
    bf16* w1sb = wop2 + C_ * C_;                 // [64][256]
    bf16* w2Tg = w1sb + 64 * C_;                 // [49][64] padded 3200

    setup_k<<<4443, 256, 0, stream>>>(spatial, semantic, rp_w1, rp_w2, op_w1, op_w2,
                                      fp_w1, fp_w2, sigma,
                                      spb, seb, wrp1, wrp2, wop1, wop2,
                                      w1ckg, w1sb, w2Tg, sk);

    // range_proj fused pair: conv+bias -> LN+SiLU -> conv+bias  => t1 = px
    conv_pair<true, 0><<<256, 256, 0, stream>>>(seb, wrp1, rp_b1, rp_g, rp_be, wrp2, rp_b2, t1);

    // sim(MFMA,LDS)+softmax+fixup+gate+renorm+gather(LDS) => t0
    attn_k<<<512, 256, 0, stream>>>(t1, spb, seb, w1sb, w1ckg, w2Tg, fp_b1, fp_b2,
                                    fp_g, fp_be, sk, t0);

    // output_proj fused pair: conv+bias -> LN -> conv+bias, fp32 channel-first out
    conv_pair<false, 1><<<256, 256, 0, stream>>>(t0, wop1, op_b1, op_g, op_be, wop2, op_b2, d_out);
}